// Round 7
// baseline (1306.981 us; speedup 1.0000x reference)
//
#include <hip/hip_runtime.h>
#include <math.h>

// ---------------- problem constants ----------------
#define H 256
#define S_STEPS 4
#define B_RXN 512
#define N_MOLS 2048          // B*S
#define ATOMS_PER_MOL 32
#define N_ATOMS 65536        // N_MOLS*32
#define N_BONDS 131072
#define NBP1 131073          // N_BONDS+1
#define MAX_NB 6
#define ATOM_FDIM 133
#define BOND_FDIM 147
#define DEPTH 3
#define N_ITERS 3

typedef unsigned short bf16u;
typedef __attribute__((ext_vector_type(8))) short short8v;  // 8 bf16 = 4 VGPR
typedef __attribute__((ext_vector_type(4))) float f32x4;

__device__ __forceinline__ float b2f(bf16u u) {
    union { unsigned int i; float f; } c; c.i = ((unsigned int)u) << 16; return c.f;
}
__device__ __forceinline__ bf16u f2b(float f) {
    union { float f; unsigned int i; } c; c.f = f;
    unsigned int i = c.i;
    return (bf16u)((i + 0x7FFFu + ((i >> 16) & 1u)) >> 16);   // RNE
}
__device__ __forceinline__ unsigned int diffpack(unsigned int a, unsigned int b) {
    float a0 = b2f((bf16u)(a & 0xFFFFu)), a1 = b2f((bf16u)(a >> 16));
    float b0 = b2f((bf16u)(b & 0xFFFFu)), b1 = b2f((bf16u)(b >> 16));
    return (unsigned int)f2b(a0 - b0) | ((unsigned int)f2b(a1 - b1) << 16);
}

// ============ bond/atom-phase MFMA GEMM: depth-2 reg prefetch, LDS dbuf, 1 barrier/step ====
// K-loop FULLY UNROLLED so prefetch-slot indices are compile-time (rule #20 fix).
// MODE 0 (WI):   A = f_bonds f32 [M,147] direct (KP=160);     out: INP=acc, MSGA=relu(acc)
// MODE 1 (MSG):  A = amsg[b2a[r]] - msg[b2revb[r]] (KP=256);  out: relu(acc+inp), row0=0
// MODE 2 (ATOM): A = [f_atoms f32 133 | pad | amsg 256] (KP=416, BN=128); out: f32 relu(acc+bias)
template<int MODE>
__global__ __launch_bounds__(256, 3) void bond_gemm_k(
    const float* __restrict__ Af32,   // MODE0: f_bonds; MODE2: f_atoms
    const bf16u* __restrict__ amsg,
    const bf16u* __restrict__ msgp,
    const bf16u* __restrict__ inp,
    const bf16u* __restrict__ WT,     // [256][KP] bf16
    const float* __restrict__ bias,
    const int* __restrict__ b2a, const int* __restrict__ b2revb,
    float* __restrict__ outf, bf16u* __restrict__ outb, bf16u* __restrict__ outb2,
    int M)
{
    constexpr int KP  = (MODE == 0) ? 160 : ((MODE == 1) ? 256 : 416);
    constexpr int NS  = KP / 32;
    constexpr int BN  = (MODE == 2) ? 128 : 256;
    constexpr int MFN = (MODE == 2) ? 2 : 4;
    constexpr int NBQ = BN / 64;

    __shared__ bf16u As[2][64][40];
    __shared__ bf16u Bs[2][BN][40];

    const int tid = threadIdx.x;
    const int lane = tid & 63, w = tid >> 6;
    const int m0 = blockIdx.x * 64;
    const int col0 = (MODE == 2) ? blockIdx.y * BN : 0;
    const int ar = tid >> 2, q = tid & 3;
    const int arow = m0 + ar;
    const bool rok = arow < M;
    const int lr = lane & 15, lk = (lane >> 4) * 8;
    const int WC  = (MODE == 2) ? (w & 1) : w;
    const int WR0 = (MODE == 2) ? (w >> 1) * 32 : 0;

    size_t o1 = 0, o2 = 0;
    if (MODE == 1) {
        int r = rok ? arow : 0;
        o1 = (size_t)b2a[r] * H;
        o2 = (size_t)b2revb[r] * H;
    }

    const uint4 z4 = {0u, 0u, 0u, 0u};
    // prefetch register slots — only ever indexed with compile-time constants
    float4 fA[2][2];
    uint4  uA[2], uB4[2];
    uint4  pB[2][NBQ];

    auto loadA = [&](int s, int sl) {
        const int kc = s * 32 + q * 8;
        if (MODE == 0) {
            const float* p = Af32 + (size_t)arow * BOND_FDIM + kc;
            if (rok && kc + 8 <= BOND_FDIM) {
                fA[sl][0] = *(const float4*)p;
                fA[sl][1] = *(const float4*)(p + 4);
            } else {
                float t[8];
                #pragma unroll
                for (int j = 0; j < 8; ++j)
                    t[j] = (rok && kc + j < BOND_FDIM) ? p[j] : 0.f;
                fA[sl][0] = make_float4(t[0], t[1], t[2], t[3]);
                fA[sl][1] = make_float4(t[4], t[5], t[6], t[7]);
            }
        } else if (MODE == 1) {
            uA[sl]  = rok ? *(const uint4*)(amsg + o1 + kc) : z4;
            uB4[sl] = rok ? *(const uint4*)(msgp + o2 + kc) : z4;
        } else {
            if (kc < 160) {
                const float* p = Af32 + (size_t)arow * ATOM_FDIM + kc;
                if (kc + 8 <= ATOM_FDIM) {
                    fA[sl][0] = *(const float4*)p;
                    fA[sl][1] = *(const float4*)(p + 4);
                } else {
                    float t[8];
                    #pragma unroll
                    for (int j = 0; j < 8; ++j)
                        t[j] = (kc + j < ATOM_FDIM) ? p[j] : 0.f;
                    fA[sl][0] = make_float4(t[0], t[1], t[2], t[3]);
                    fA[sl][1] = make_float4(t[4], t[5], t[6], t[7]);
                }
            } else {
                uA[sl] = *(const uint4*)(amsg + (size_t)arow * H + (kc - 160));
            }
        }
    };
    auto writeA = [&](int s, int sl) {
        bf16u* dst = &As[s & 1][ar][q * 8];
        if (MODE == 1) {
            uint4 v = uA[sl], u2 = uB4[sl];
            v.x = diffpack(v.x, u2.x); v.y = diffpack(v.y, u2.y);
            v.z = diffpack(v.z, u2.z); v.w = diffpack(v.w, u2.w);
            *(uint4*)dst = v;
        } else if (MODE == 0 || s * 32 < 160) {
            float4 f0 = fA[sl][0], f1 = fA[sl][1];
            ushort4 s0, s1;
            s0.x = f2b(f0.x); s0.y = f2b(f0.y); s0.z = f2b(f0.z); s0.w = f2b(f0.w);
            s1.x = f2b(f1.x); s1.y = f2b(f1.y); s1.z = f2b(f1.z); s1.w = f2b(f1.w);
            *(ushort4*)dst = s0;
            *(ushort4*)(dst + 4) = s1;
        } else {
            *(uint4*)dst = uA[sl];
        }
    };
    auto loadB = [&](int s, int sl) {
        #pragma unroll
        for (int i = 0; i < NBQ; ++i) {
            int id = tid * NBQ + i; int n = id >> 2, kq = id & 3;
            pB[sl][i] = *(const uint4*)(WT + (size_t)(col0 + n) * KP + s * 32 + kq * 8);
        }
    };
    auto writeB = [&](int s, int sl) {
        #pragma unroll
        for (int i = 0; i < NBQ; ++i) {
            int id = tid * NBQ + i; int n = id >> 2, kq = id & 3;
            *(uint4*)&Bs[s & 1][n][kq * 8] = pB[sl][i];
        }
    };

    f32x4 acc[MFN][4];
    const f32x4 zf = {0.f, 0.f, 0.f, 0.f};
    #pragma unroll
    for (int i = 0; i < MFN; ++i)
        #pragma unroll
        for (int j = 0; j < 4; ++j) acc[i][j] = zf;

    // prologue: tiles 0,1 into reg slots 0,1; stage tile 0
    loadA(0, 0); loadB(0, 0);
    loadA(1, 1); loadB(1, 1);
    writeA(0, 0); writeB(0, 0);
    __syncthreads();

    // FULLY UNROLLED K loop: s, sl, nx are compile-time -> slots stay in VGPRs
    #pragma unroll
    for (int s = 0; s < NS; ++s) {
        const int sl = s & 1, nx = sl ^ 1;
        if (s + 2 < NS) { loadA(s + 2, sl); loadB(s + 2, sl); }   // depth-2 prefetch
        short8v a[MFN], b[4];
        #pragma unroll
        for (int mf = 0; mf < MFN; ++mf)
            a[mf] = *(const short8v*)&As[sl][WR0 + mf * 16 + lr][lk];
        #pragma unroll
        for (int nf = 0; nf < 4; ++nf)
            b[nf] = *(const short8v*)&Bs[sl][WC * 64 + nf * 16 + lr][lk];
        #pragma unroll
        for (int mf = 0; mf < MFN; ++mf)
            #pragma unroll
            for (int nf = 0; nf < 4; ++nf)
                acc[mf][nf] = __builtin_amdgcn_mfma_f32_16x16x32_bf16(
                    a[mf], b[nf], acc[mf][nf], 0, 0, 0);
        if (s + 1 < NS) {
            writeA(s + 1, nx); writeB(s + 1, nx);
            __syncthreads();
        }
    }

    // ---- epilogue ----
    const int rbase = (lane >> 4) * 4;
    #pragma unroll
    for (int mf = 0; mf < MFN; ++mf) {
        #pragma unroll
        for (int nf = 0; nf < 4; ++nf) {
            const int col = col0 + WC * 64 + nf * 16 + lr;
            #pragma unroll
            for (int r = 0; r < 4; ++r) {
                const int row = m0 + WR0 + mf * 16 + rbase + r;
                if (row >= M) continue;
                float v = acc[mf][nf][r];
                const size_t off = (size_t)row * H + col;
                if (MODE == 0) {
                    outb[off] = f2b(v);
                    outb2[off] = f2b(fmaxf(v, 0.f));
                } else if (MODE == 1) {
                    v += b2f(inp[off]);
                    v = fmaxf(v, 0.f);
                    outb[off] = (row == 0) ? (bf16u)0 : f2b(v);
                } else {
                    v += bias[col];
                    outf[off] = fmaxf(v, 0.f);
                }
            }
        }
    }
}

// ================= generic MFMA linear (mid phase) — unchanged =========
template<bool BIAS>
__global__ __launch_bounds__(256) void mfma_lin_k(
    const float* __restrict__ A1, int lda1, int KA1,
    const float* __restrict__ A2, int lda2,
    const bf16u* __restrict__ WT,
    const float* __restrict__ bias,
    float* __restrict__ C, int N, int K)
{
    __shared__ bf16u As[64][40];
    __shared__ bf16u Bs[256][40];
    const int tid = threadIdx.x;
    const int lane = tid & 63, w = tid >> 6;
    const int m0 = blockIdx.x * 64;
    const int col0 = blockIdx.y * 256;
    const int ar = tid >> 2, ac8 = (tid & 3) * 8;
    const int arow = m0 + ar;
    const int lr = lane & 15, lk = (lane >> 4) * 8;

    f32x4 acc[4][4];
    const f32x4 zf = {0.f, 0.f, 0.f, 0.f};
    #pragma unroll
    for (int i = 0; i < 4; ++i)
        #pragma unroll
        for (int j = 0; j < 4; ++j) acc[i][j] = zf;

    for (int k0 = 0; k0 < K; k0 += 32) {
        float v[8];
        #pragma unroll
        for (int j = 0; j < 8; ++j) {
            int kk = k0 + ac8 + j;
            v[j] = (kk < KA1) ? A1[(size_t)arow * lda1 + kk]
                              : A2[(size_t)arow * lda2 + (kk - KA1)];
        }
        ushort4 s0, s1;
        s0.x = f2b(v[0]); s0.y = f2b(v[1]); s0.z = f2b(v[2]); s0.w = f2b(v[3]);
        s1.x = f2b(v[4]); s1.y = f2b(v[5]); s1.z = f2b(v[6]); s1.w = f2b(v[7]);
        *(ushort4*)&As[ar][ac8] = s0;
        *(ushort4*)&As[ar][ac8 + 4] = s1;
        {
            const bf16u* bp = WT + (size_t)(col0 + tid) * K + k0;
            uint4 q0 = *(const uint4*)(bp);
            uint4 q1 = *(const uint4*)(bp + 8);
            uint4 q2 = *(const uint4*)(bp + 16);
            uint4 q3 = *(const uint4*)(bp + 24);
            *(uint4*)&Bs[tid][0]  = q0;
            *(uint4*)&Bs[tid][8]  = q1;
            *(uint4*)&Bs[tid][16] = q2;
            *(uint4*)&Bs[tid][24] = q3;
        }
        __syncthreads();
        short8v a[4], b[4];
        #pragma unroll
        for (int mf = 0; mf < 4; ++mf)
            a[mf] = *(const short8v*)&As[mf * 16 + lr][lk];
        #pragma unroll
        for (int nf = 0; nf < 4; ++nf)
            b[nf] = *(const short8v*)&Bs[w * 64 + nf * 16 + lr][lk];
        #pragma unroll
        for (int mf = 0; mf < 4; ++mf)
            #pragma unroll
            for (int nf = 0; nf < 4; ++nf)
                acc[mf][nf] = __builtin_amdgcn_mfma_f32_16x16x32_bf16(
                    a[mf], b[nf], acc[mf][nf], 0, 0, 0);
        __syncthreads();
    }

    const int rbase = (lane >> 4) * 4;
    #pragma unroll
    for (int mf = 0; mf < 4; ++mf) {
        #pragma unroll
        for (int nf = 0; nf < 4; ++nf) {
            const int col = col0 + w * 64 + nf * 16 + lr;
            #pragma unroll
            for (int r = 0; r < 4; ++r) {
                const int row = m0 + mf * 16 + rbase + r;
                float v = acc[mf][nf][r];
                if (BIAS) v += bias[col];
                C[(size_t)row * N + col] = v;
            }
        }
    }
}

// ---------------- prep kernels ----------------
__global__ __launch_bounds__(256) void prep_wt_k(const float* __restrict__ W,
                                                 bf16u* __restrict__ WT, int K, int KP)
{
    int idx = blockIdx.x * 256 + threadIdx.x;
    if (idx >= 256 * KP) return;
    int n = idx / KP, k = idx - n * KP;
    WT[idx] = (k < K) ? f2b(W[(size_t)k * H + n]) : (bf16u)0;
}

__global__ __launch_bounds__(256) void prep_wto_k(const float* __restrict__ Wo,
                                                  bf16u* __restrict__ WT)
{
    int idx = blockIdx.x * 256 + threadIdx.x;
    if (idx >= 256 * 416) return;
    int n = idx / 416, k = idx - n * 416;
    float v = 0.f;
    if (k < ATOM_FDIM) v = Wo[(size_t)k * H + n];
    else if (k >= 160) v = Wo[(size_t)(ATOM_FDIM + k - 160) * H + n];
    WT[idx] = f2b(v);
}

__global__ __launch_bounds__(256) void prep_wt_t_k(const float* __restrict__ W,
                                                   bf16u* __restrict__ WT, int K)
{
    int idx = blockIdx.x * 256 + threadIdx.x;
    if (idx >= 256 * K) return;
    int n = idx / K, k = idx - n * K;
    WT[idx] = f2b(W[(size_t)k * 256 + n]);
}

__global__ __launch_bounds__(256) void prep_wt_gates_k(const float* __restrict__ Wih,
                                                       const float* __restrict__ Whh,
                                                       bf16u* __restrict__ WT)
{
    int idx = blockIdx.x * 256 + threadIdx.x;
    if (idx >= 1024 * 768) return;
    int n = idx / 768, k = idx - n * 768;
    WT[idx] = f2b(k < 512 ? Wih[(size_t)n * 512 + k] : Whh[(size_t)n * 256 + (k - 512)]);
}

// ---------------- small kernels ----------------
__global__ __launch_bounds__(256) void gather6_bf16_k(const bf16u* __restrict__ msg,
                                                      const int* __restrict__ a2b,
                                                      bf16u* __restrict__ outb)
{
    int idx = blockIdx.x * 256 + threadIdx.x;
    if (idx >= N_ATOMS * (H / 8)) return;
    int na = idx >> 5, c = idx & 31;
    const int* nb = a2b + (size_t)na * MAX_NB;
    float s[8] = {0.f, 0.f, 0.f, 0.f, 0.f, 0.f, 0.f, 0.f};
    #pragma unroll
    for (int j = 0; j < MAX_NB; ++j) {
        uint4 u = *(const uint4*)(msg + (size_t)nb[j] * H + c * 8);
        s[0] += b2f((bf16u)(u.x & 0xFFFFu)); s[1] += b2f((bf16u)(u.x >> 16));
        s[2] += b2f((bf16u)(u.y & 0xFFFFu)); s[3] += b2f((bf16u)(u.y >> 16));
        s[4] += b2f((bf16u)(u.z & 0xFFFFu)); s[5] += b2f((bf16u)(u.z >> 16));
        s[6] += b2f((bf16u)(u.w & 0xFFFFu)); s[7] += b2f((bf16u)(u.w >> 16));
    }
    uint4 o;
    o.x = (unsigned int)f2b(s[0]) | ((unsigned int)f2b(s[1]) << 16);
    o.y = (unsigned int)f2b(s[2]) | ((unsigned int)f2b(s[3]) << 16);
    o.z = (unsigned int)f2b(s[4]) | ((unsigned int)f2b(s[5]) << 16);
    o.w = (unsigned int)f2b(s[6]) | ((unsigned int)f2b(s[7]) << 16);
    *(uint4*)(outb + (size_t)na * H + c * 8) = o;
}

__global__ __launch_bounds__(256) void zero_f32_k(float* __restrict__ p, int n)
{
    int idx = blockIdx.x * 256 + threadIdx.x;
    if (idx < n) p[idx] = 0.f;
}

__device__ __forceinline__ float sigm(float x) { return 1.f / (1.f + expf(-x)); }

__global__ __launch_bounds__(256) void lstm_pw_k(const float* __restrict__ gates,
                                                 float* __restrict__ h,
                                                 float* __restrict__ c, int M)
{
    int idx = blockIdx.x * 256 + threadIdx.x;
    if (idx >= M * H) return;
    int m = idx >> 8, d = idx & 255;
    const float* g = gates + (size_t)m * (4 * H);
    float ig = sigm(g[d]);
    float fg = sigm(g[H + d]);
    float gg = tanhf(g[2 * H + d]);
    float og = sigm(g[3 * H + d]);
    float cn = fg * c[idx] + ig * gg;
    c[idx] = cn;
    h[idx] = og * tanhf(cn);
}

__global__ __launch_bounds__(256) void s2s_attn_k(const float* __restrict__ feat,
                                                  const float* __restrict__ h,
                                                  float* __restrict__ q_star, int Nn)
{
    int m = blockIdx.x;
    int t = threadIdx.x;
    int lane = t & 63, wave = t >> 6;
    __shared__ float sc[32];
    const float* f = feat + (size_t)m * Nn * H;
    const float* hm = h + (size_t)m * H;
    for (int n = wave; n < Nn; n += 4) {
        const float* fr = f + (size_t)n * H;
        float p = 0.f;
        #pragma unroll
        for (int u = 0; u < 4; ++u) p += fr[lane * 4 + u] * hm[lane * 4 + u];
        #pragma unroll
        for (int o = 32; o >= 1; o >>= 1) p += __shfl_xor(p, o);
        if (lane == 0) sc[n] = p;
    }
    __syncthreads();
    float mx = -1e30f;
    for (int n = 0; n < Nn; ++n) mx = fmaxf(mx, sc[n]);
    float ssum = 0.f, r = 0.f;
    for (int n = 0; n < Nn; ++n) {
        float a = expf(sc[n] - mx);
        ssum += a;
        r += a * f[(size_t)n * H + t];
    }
    r /= ssum;
    q_star[(size_t)m * (2 * H) + t] = hm[t];
    q_star[(size_t)m * (2 * H) + H + t] = r;
}

__global__ __launch_bounds__(256) void build_x_k(const float* __restrict__ P,
                                                 const float* __restrict__ Q,
                                                 const float* __restrict__ SO,
                                                 const float* __restrict__ b0,
                                                 float* __restrict__ X)
{
    int idx = blockIdx.x * 256 + threadIdx.x;
    if (idx >= B_RXN * S_STEPS * S_STEPS * H) return;
    int d  = idx & 255;
    int s2 = (idx >> 8) & 3;
    int s1 = (idx >> 10) & 3;
    int b  = idx >> 12;
    float v;
    if (s1 == s2) v = SO[((size_t)b * S_STEPS + s1) * H + d];
    else v = P[((size_t)b * S_STEPS + s1) * H + d] + Q[((size_t)b * S_STEPS + s2) * H + d] + b0[d];
    X[idx] = v;
}

// ---------------- launch ----------------
extern "C" void kernel_launch(void* const* d_in, const int* in_sizes, int n_in,
                              void* d_out, int out_size, void* d_ws, size_t ws_size,
                              hipStream_t stream)
{
    const float* f_atoms   = (const float*)d_in[0];
    const float* f_bonds   = (const float*)d_in[1];
    const int*   a2b       = (const int*)d_in[2];
    const int*   b2a       = (const int*)d_in[3];
    const int*   b2revb    = (const int*)d_in[4];
    const float* W_i       = (const float*)d_in[5];
    const float* W_h       = (const float*)d_in[6];
    const float* W_o       = (const float*)d_in[7];
    const float* b_o       = (const float*)d_in[8];
    const float* W_nn0     = (const float*)d_in[9];
    const float* b_nn0     = (const float*)d_in[10];
    const float* W_nn0s    = (const float*)d_in[11];
    const float* b_nn0s    = (const float*)d_in[12];
    const float* W_nn1     = (const float*)d_in[13];
    const float* b_nn1     = (const float*)d_in[14];
    const float* lstm_n_Wih = (const float*)d_in[15];
    const float* lstm_n_Whh = (const float*)d_in[16];
    const float* lstm_n_b   = (const float*)d_in[17];
    const float* node_cond_W = (const float*)d_in[18];
    const float* node_cond_b = (const float*)d_in[19];
    const float* lstm_g_Wih = (const float*)d_in[20];
    const float* lstm_g_Whh = (const float*)d_in[21];
    const float* lstm_g_b   = (const float*)d_in[22];
    const float* graph_cond_W = (const float*)d_in[23];
    const float* graph_cond_b = (const float*)d_in[24];
    float* out = (float*)d_out;

    // ---- workspace layout ----
    const size_t SZB = (size_t)NBP1 * H * sizeof(bf16u);    // 67,109,376 B
    char* base = (char*)d_ws;
    bf16u* INP  = (bf16u*)(base);
    bf16u* MSGA = (bf16u*)(base + SZB);
    bf16u* MSGB = (bf16u*)(base + 2 * SZB);
    bf16u* AMSG = (bf16u*)(base + 3 * SZB);                 // [N_ATOMS,H] bf16
    bf16u* WT_I = (bf16u*)(base + 3 * SZB + 33554432);      // [256][160]
    bf16u* WT_H = (bf16u*)(base + 3 * SZB + 33636352);      // [256][256]
    bf16u* WT_O = (bf16u*)(base + 3 * SZB + 33767424);      // [256][416]
    // aliases (regions dead at time of use):
    float* ATOMH = (float*)(base);                          // [N_ATOMS,H] f32, alias INP
    float* SMALL = (float*)(base + SZB);                    // f32 scratch, alias MSGA
    float* GATES  = SMALL;
    float* HN     = SMALL + 2097152;
    float* CN     = SMALL + 2621440;
    float* QSTARN = SMALL + 3145728;
    float* MOL    = SMALL + 4194304;
    float* PP     = SMALL + 4718592;
    float* QQ     = SMALL + 5242880;
    float* SO     = SMALL + 5767168;
    float* XBUF   = SMALL + 6291456;
    float* STEPS  = SMALL + 8388608;
    float* HG     = SMALL + 8912896;
    float* CG     = SMALL + 9043968;
    float* QSTARG = SMALL + 9175040;
    float* GATESG = SMALL + 9437184;
    char* sm2 = base + SZB + 41943040;
    bf16u* WTG_N = (bf16u*)(sm2);
    bf16u* WTG_G = (bf16u*)(sm2 + 1572864);
    bf16u* WT_NC = (bf16u*)(sm2 + 3145728);
    bf16u* WT_P  = (bf16u*)(sm2 + 3407872);
    bf16u* WT_Q  = (bf16u*)(sm2 + 3538944);
    bf16u* WT_S  = (bf16u*)(sm2 + 3670016);
    bf16u* WT_N1 = (bf16u*)(sm2 + 3801088);
    bf16u* WT_GC = (bf16u*)(sm2 + 4325376);

    dim3 blk(256);
    const int MB_BOND = (NBP1 + 63) / 64;     // 2049
    const int MB_ATOM = N_ATOMS / 64;         // 1024

    // 0. weight prep
    prep_wt_k<<<(256 * 160 + 255) / 256, blk, 0, stream>>>(W_i, WT_I, BOND_FDIM, 160);
    prep_wt_k<<<(256 * 256 + 255) / 256, blk, 0, stream>>>(W_h, WT_H, H, 256);
    prep_wto_k<<<(256 * 416 + 255) / 256, blk, 0, stream>>>(W_o, WT_O);

    // 1. inp = f_bonds @ W_i -> INP (bf16) ; MSGA = relu(inp) (fused)
    bond_gemm_k<0><<<MB_BOND, blk, 0, stream>>>(
        f_bonds, nullptr, nullptr, nullptr, WT_I, nullptr, nullptr, nullptr,
        nullptr, INP, MSGA, NBP1);

    // 2. depth loop
    bf16u* cur = MSGA; bf16u* nxt = MSGB;
    for (int d = 0; d < DEPTH - 1; ++d) {
        gather6_bf16_k<<<(N_ATOMS * (H / 8) + 255) / 256, blk, 0, stream>>>(cur, a2b, AMSG);
        bond_gemm_k<1><<<MB_BOND, blk, 0, stream>>>(
            nullptr, AMSG, cur, INP, WT_H, nullptr, b2a, b2revb,
            nullptr, nxt, nullptr, NBP1);
        bf16u* t = cur; cur = nxt; nxt = t;
    }

    // 3. nei = gather-sum(final message)  (cur == MSGA)
    gather6_bf16_k<<<(N_ATOMS * (H / 8) + 255) / 256, blk, 0, stream>>>(cur, a2b, AMSG);

    // 3b. mid-phase weight prep (MSGA region now dead)
    prep_wt_gates_k<<<(1024 * 768 + 255) / 256, blk, 0, stream>>>(lstm_n_Wih, lstm_n_Whh, WTG_N);
    prep_wt_gates_k<<<(1024 * 768 + 255) / 256, blk, 0, stream>>>(lstm_g_Wih, lstm_g_Whh, WTG_G);
    prep_wt_t_k<<<(256 * 512 + 255) / 256, blk, 0, stream>>>(node_cond_W, WT_NC, 512);
    prep_wt_t_k<<<(256 * 256 + 255) / 256, blk, 0, stream>>>(W_nn0, WT_P, 256);
    prep_wt_t_k<<<(256 * 256 + 255) / 256, blk, 0, stream>>>(W_nn0 + 256 * 256, WT_Q, 256);
    prep_wt_t_k<<<(256 * 256 + 255) / 256, blk, 0, stream>>>(W_nn0s, WT_S, 256);
    prep_wt_t_k<<<(256 * 1024 + 255) / 256, blk, 0, stream>>>(W_nn1, WT_N1, 1024);
    prep_wt_t_k<<<(256 * 512 + 255) / 256, blk, 0, stream>>>(graph_cond_W, WT_GC, 512);

    // 4. atom_h = relu([f_atoms, nei] @ W_o + b_o) -> ATOMH f32 (aliases dead INP)
    bond_gemm_k<2><<<dim3(MB_ATOM, 2), blk, 0, stream>>>(
        f_atoms, AMSG, nullptr, nullptr, WT_O, b_o, nullptr, nullptr,
        ATOMH, nullptr, nullptr, N_ATOMS);

    // 5. node Set2Set over [2048, 32, 256]
    zero_f32_k<<<(2097152 + 255) / 256, blk, 0, stream>>>(HN, 2097152);  // HN,CN,QSTARN
    for (int it = 0; it < N_ITERS; ++it) {
        mfma_lin_k<true><<<dim3(N_MOLS / 64, 4), blk, 0, stream>>>(
            QSTARN, 2 * H, 2 * H, HN, H, WTG_N, lstm_n_b, GATES, 4 * H, 3 * H);
        lstm_pw_k<<<(N_MOLS * H) / 256, blk, 0, stream>>>(GATES, HN, CN, N_MOLS);
        s2s_attn_k<<<N_MOLS, blk, 0, stream>>>(ATOMH, HN, QSTARN, ATOMS_PER_MOL);
    }
    mfma_lin_k<true><<<dim3(N_MOLS / 64, 1), blk, 0, stream>>>(
        QSTARN, 2 * H, 2 * H, QSTARN, 2 * H, WT_NC, node_cond_b, MOL, H, 2 * H);

    // 6. NN attention over steps
    mfma_lin_k<false><<<dim3(N_MOLS / 64, 1), blk, 0, stream>>>(
        MOL, H, H, MOL, H, WT_P, nullptr, PP, H, H);
    mfma_lin_k<false><<<dim3(N_MOLS / 64, 1), blk, 0, stream>>>(
        MOL, H, H, MOL, H, WT_Q, nullptr, QQ, H, H);
    mfma_lin_k<true><<<dim3(N_MOLS / 64, 1), blk, 0, stream>>>(
        MOL, H, H, MOL, H, WT_S, b_nn0s, SO, H, H);
    build_x_k<<<(B_RXN * 16 * H) / 256, blk, 0, stream>>>(PP, QQ, SO, b_nn0, XBUF);
    mfma_lin_k<true><<<dim3(N_MOLS / 64, 1), blk, 0, stream>>>(
        XBUF, S_STEPS * H, S_STEPS * H, XBUF, S_STEPS * H, WT_N1, b_nn1, STEPS, H, S_STEPS * H);

    // 7. graph Set2Set over [512, 4, 256]
    zero_f32_k<<<(524288 + 255) / 256, blk, 0, stream>>>(HG, 524288);    // HG,CG,QSTARG
    for (int it = 0; it < N_ITERS; ++it) {
        mfma_lin_k<true><<<dim3(B_RXN / 64, 4), blk, 0, stream>>>(
            QSTARG, 2 * H, 2 * H, HG, H, WTG_G, lstm_g_b, GATESG, 4 * H, 3 * H);
        lstm_pw_k<<<(B_RXN * H) / 256, blk, 0, stream>>>(GATESG, HG, CG, B_RXN);
        s2s_attn_k<<<B_RXN, blk, 0, stream>>>(STEPS, HG, QSTARG, S_STEPS);
    }

    // 8. out
    mfma_lin_k<true><<<dim3(B_RXN / 64, 1), blk, 0, stream>>>(
        QSTARG, 2 * H, 2 * H, QSTARG, 2 * H, WT_GC, graph_cond_b, out, H, 2 * H);
}

// Round 8
// 1059.124 us; speedup vs baseline: 1.2340x; 1.2340x over previous
//
#include <hip/hip_runtime.h>
#include <math.h>

// ---------------- problem constants ----------------
#define H 256
#define S_STEPS 4
#define B_RXN 512
#define N_MOLS 2048          // B*S
#define ATOMS_PER_MOL 32
#define N_ATOMS 65536        // N_MOLS*32
#define N_BONDS 131072
#define NBP1 131073          // N_BONDS+1
#define MAX_NB 6
#define ATOM_FDIM 133
#define BOND_FDIM 147
#define DEPTH 3
#define N_ITERS 3

typedef unsigned short bf16u;
typedef __attribute__((ext_vector_type(8))) short short8v;  // 8 bf16 = 4 VGPR
typedef __attribute__((ext_vector_type(4))) float f32x4;

__device__ __forceinline__ float b2f(bf16u u) {
    union { unsigned int i; float f; } c; c.i = ((unsigned int)u) << 16; return c.f;
}
__device__ __forceinline__ bf16u f2b(float f) {
    union { float f; unsigned int i; } c; c.f = f;
    unsigned int i = c.i;
    return (bf16u)((i + 0x7FFFu + ((i >> 16) & 1u)) >> 16);   // RNE
}

// ============ dense MFMA GEMM (bond/atom phase): C[M,256] = epi(A[M,KP] @ WT^T) ============
// A is CONTIGUOUS bf16 (1 uint4 per thread per k-step). Round-3 proven structure:
// single-buffer LDS, 2 barriers/step.
// MODE 0 (WI):   A = FB16 [M,160];              epi: INP=acc (bf16), MSG=relu(acc) (bf16)
// MODE 1 (MW):   A = msg  [M,256];              epi: MW=acc (bf16)
// MODE 2 (ATOM): A = [FA16 160 | AMSG 256] (KP=416); epi: f32 relu(acc+bias)
template<int MODE>
__global__ __launch_bounds__(256) void dense_gemm_k(
    const bf16u* __restrict__ A1,
    const bf16u* __restrict__ A2,     // MODE2 only
    const bf16u* __restrict__ WT,     // [256][KP] bf16
    const float* __restrict__ bias,   // MODE2 only
    float* __restrict__ outf,
    bf16u* __restrict__ outb, bf16u* __restrict__ outb2,
    int M)
{
    constexpr int KP = (MODE == 0) ? 160 : ((MODE == 1) ? 256 : 416);
    __shared__ bf16u As[64][40];
    __shared__ bf16u Bs[256][40];

    const int tid = threadIdx.x;
    const int lane = tid & 63, w = tid >> 6;
    const int m0 = blockIdx.x * 64;
    const int ar = tid >> 2, q8 = (tid & 3) * 8;
    const int arow = m0 + ar;
    const bool rok = arow < M;
    const int lr = lane & 15, lk = (lane >> 4) * 8;
    const uint4 z4 = {0u, 0u, 0u, 0u};

    f32x4 acc[4][4];
    const f32x4 zf = {0.f, 0.f, 0.f, 0.f};
    #pragma unroll
    for (int i = 0; i < 4; ++i)
        #pragma unroll
        for (int j = 0; j < 4; ++j) acc[i][j] = zf;

    for (int k0 = 0; k0 < KP; k0 += 32) {
        // ---- stage A: one contiguous uint4 per thread ----
        const int kc = k0 + q8;
        uint4 va;
        if (MODE == 2) {
            va = (kc < 160) ? *(const uint4*)(A1 + (size_t)arow * 160 + kc)
                            : *(const uint4*)(A2 + (size_t)arow * 256 + (kc - 160));
        } else {
            constexpr int LDA = (MODE == 0) ? 160 : 256;
            va = rok ? *(const uint4*)(A1 + (size_t)arow * LDA + kc) : z4;
        }
        *(uint4*)&As[ar][q8] = va;
        // ---- stage B: thread t = row n of WT, 4 uint4 ----
        {
            const bf16u* bp = WT + (size_t)tid * KP + k0;
            uint4 q0 = *(const uint4*)(bp);
            uint4 q1 = *(const uint4*)(bp + 8);
            uint4 q2 = *(const uint4*)(bp + 16);
            uint4 q3 = *(const uint4*)(bp + 24);
            *(uint4*)&Bs[tid][0]  = q0;
            *(uint4*)&Bs[tid][8]  = q1;
            *(uint4*)&Bs[tid][16] = q2;
            *(uint4*)&Bs[tid][24] = q3;
        }
        __syncthreads();

        short8v a[4], b[4];
        #pragma unroll
        for (int mf = 0; mf < 4; ++mf)
            a[mf] = *(const short8v*)&As[mf * 16 + lr][lk];
        #pragma unroll
        for (int nf = 0; nf < 4; ++nf)
            b[nf] = *(const short8v*)&Bs[w * 64 + nf * 16 + lr][lk];
        #pragma unroll
        for (int mf = 0; mf < 4; ++mf)
            #pragma unroll
            for (int nf = 0; nf < 4; ++nf)
                acc[mf][nf] = __builtin_amdgcn_mfma_f32_16x16x32_bf16(
                    a[mf], b[nf], acc[mf][nf], 0, 0, 0);
        __syncthreads();
    }

    const int rbase = (lane >> 4) * 4;
    #pragma unroll
    for (int mf = 0; mf < 4; ++mf) {
        #pragma unroll
        for (int nf = 0; nf < 4; ++nf) {
            const int col = w * 64 + nf * 16 + lr;
            #pragma unroll
            for (int r = 0; r < 4; ++r) {
                const int row = m0 + mf * 16 + rbase + r;
                if (row >= M) continue;
                float v = acc[mf][nf][r];
                const size_t off = (size_t)row * H + col;
                if (MODE == 0) {
                    outb[off] = f2b(v);                      // INP
                    outb2[off] = f2b(fmaxf(v, 0.f));         // MSG (row0: inp=0 -> 0)
                } else if (MODE == 1) {
                    outb[off] = f2b(v);                      // MW (row0: msg=0 -> 0)
                } else {
                    v += bias[col];
                    outf[off] = fmaxf(v, 0.f);
                }
            }
        }
    }
}

// ---- combine: msg[b] = relu(inp[b] + AP[b2a[b]] - MW[b2revb[b]]), row 0 = 0 ----
__global__ __launch_bounds__(256) void combine_k(
    const bf16u* __restrict__ inp, const bf16u* __restrict__ AP,
    const bf16u* __restrict__ MW,
    const int* __restrict__ b2a, const int* __restrict__ b2revb,
    bf16u* __restrict__ msg)
{
    int idx = blockIdx.x * 256 + threadIdx.x;
    if (idx >= NBP1 * 32) return;
    int b = idx >> 5, c = (idx & 31) * 8;
    bf16u* op = msg + (size_t)b * H + c;
    if (b == 0) {
        *(uint4*)op = make_uint4(0u, 0u, 0u, 0u);
        return;
    }
    int a = b2a[b], rb = b2revb[b];
    uint4 ui = *(const uint4*)(inp + (size_t)b * H + c);
    uint4 up = *(const uint4*)(AP + (size_t)a * H + c);
    uint4 um = *(const uint4*)(MW + (size_t)rb * H + c);
    uint4 o;
    unsigned int* pi = &ui.x; unsigned int* pp = &up.x;
    unsigned int* pm = &um.x; unsigned int* po = &o.x;
    #pragma unroll
    for (int t = 0; t < 4; ++t) {
        float lo = b2f((bf16u)(pi[t] & 0xFFFFu)) + b2f((bf16u)(pp[t] & 0xFFFFu))
                 - b2f((bf16u)(pm[t] & 0xFFFFu));
        float hi = b2f((bf16u)(pi[t] >> 16)) + b2f((bf16u)(pp[t] >> 16))
                 - b2f((bf16u)(pm[t] >> 16));
        lo = fmaxf(lo, 0.f); hi = fmaxf(hi, 0.f);
        po[t] = (unsigned int)f2b(lo) | ((unsigned int)f2b(hi) << 16);
    }
    *(uint4*)op = o;
}

// ================= generic MFMA linear (mid phase) — unchanged =========
template<bool BIAS>
__global__ __launch_bounds__(256) void mfma_lin_k(
    const float* __restrict__ A1, int lda1, int KA1,
    const float* __restrict__ A2, int lda2,
    const bf16u* __restrict__ WT,
    const float* __restrict__ bias,
    float* __restrict__ C, int N, int K)
{
    __shared__ bf16u As[64][40];
    __shared__ bf16u Bs[256][40];
    const int tid = threadIdx.x;
    const int lane = tid & 63, w = tid >> 6;
    const int m0 = blockIdx.x * 64;
    const int col0 = blockIdx.y * 256;
    const int ar = tid >> 2, ac8 = (tid & 3) * 8;
    const int arow = m0 + ar;
    const int lr = lane & 15, lk = (lane >> 4) * 8;

    f32x4 acc[4][4];
    const f32x4 zf = {0.f, 0.f, 0.f, 0.f};
    #pragma unroll
    for (int i = 0; i < 4; ++i)
        #pragma unroll
        for (int j = 0; j < 4; ++j) acc[i][j] = zf;

    for (int k0 = 0; k0 < K; k0 += 32) {
        float v[8];
        #pragma unroll
        for (int j = 0; j < 8; ++j) {
            int kk = k0 + ac8 + j;
            v[j] = (kk < KA1) ? A1[(size_t)arow * lda1 + kk]
                              : A2[(size_t)arow * lda2 + (kk - KA1)];
        }
        ushort4 s0, s1;
        s0.x = f2b(v[0]); s0.y = f2b(v[1]); s0.z = f2b(v[2]); s0.w = f2b(v[3]);
        s1.x = f2b(v[4]); s1.y = f2b(v[5]); s1.z = f2b(v[6]); s1.w = f2b(v[7]);
        *(ushort4*)&As[ar][ac8] = s0;
        *(ushort4*)&As[ar][ac8 + 4] = s1;
        {
            const bf16u* bp = WT + (size_t)(col0 + tid) * K + k0;
            uint4 q0 = *(const uint4*)(bp);
            uint4 q1 = *(const uint4*)(bp + 8);
            uint4 q2 = *(const uint4*)(bp + 16);
            uint4 q3 = *(const uint4*)(bp + 24);
            *(uint4*)&Bs[tid][0]  = q0;
            *(uint4*)&Bs[tid][8]  = q1;
            *(uint4*)&Bs[tid][16] = q2;
            *(uint4*)&Bs[tid][24] = q3;
        }
        __syncthreads();
        short8v a[4], b[4];
        #pragma unroll
        for (int mf = 0; mf < 4; ++mf)
            a[mf] = *(const short8v*)&As[mf * 16 + lr][lk];
        #pragma unroll
        for (int nf = 0; nf < 4; ++nf)
            b[nf] = *(const short8v*)&Bs[w * 64 + nf * 16 + lr][lk];
        #pragma unroll
        for (int mf = 0; mf < 4; ++mf)
            #pragma unroll
            for (int nf = 0; nf < 4; ++nf)
                acc[mf][nf] = __builtin_amdgcn_mfma_f32_16x16x32_bf16(
                    a[mf], b[nf], acc[mf][nf], 0, 0, 0);
        __syncthreads();
    }

    const int rbase = (lane >> 4) * 4;
    #pragma unroll
    for (int mf = 0; mf < 4; ++mf) {
        #pragma unroll
        for (int nf = 0; nf < 4; ++nf) {
            const int col = col0 + w * 64 + nf * 16 + lr;
            #pragma unroll
            for (int r = 0; r < 4; ++r) {
                const int row = m0 + mf * 16 + rbase + r;
                float v = acc[mf][nf][r];
                if (BIAS) v += bias[col];
                C[(size_t)row * N + col] = v;
            }
        }
    }
}

// ---------------- prep kernels ----------------
__global__ __launch_bounds__(256) void prep_wt_k(const float* __restrict__ W,
                                                 bf16u* __restrict__ WT, int K, int KP)
{
    int idx = blockIdx.x * 256 + threadIdx.x;
    if (idx >= 256 * KP) return;
    int n = idx / KP, k = idx - n * KP;
    WT[idx] = (k < K) ? f2b(W[(size_t)k * H + n]) : (bf16u)0;
}

__global__ __launch_bounds__(256) void prep_wto_k(const float* __restrict__ Wo,
                                                  bf16u* __restrict__ WT)
{
    int idx = blockIdx.x * 256 + threadIdx.x;
    if (idx >= 256 * 416) return;
    int n = idx / 416, k = idx - n * 416;
    float v = 0.f;
    if (k < ATOM_FDIM) v = Wo[(size_t)k * H + n];
    else if (k >= 160) v = Wo[(size_t)(ATOM_FDIM + k - 160) * H + n];
    WT[idx] = f2b(v);
}

__global__ __launch_bounds__(256) void prep_wt_t_k(const float* __restrict__ W,
                                                   bf16u* __restrict__ WT, int K)
{
    int idx = blockIdx.x * 256 + threadIdx.x;
    if (idx >= 256 * K) return;
    int n = idx / K, k = idx - n * K;
    WT[idx] = f2b(W[(size_t)k * 256 + n]);
}

__global__ __launch_bounds__(256) void prep_wt_gates_k(const float* __restrict__ Wih,
                                                       const float* __restrict__ Whh,
                                                       bf16u* __restrict__ WT)
{
    int idx = blockIdx.x * 256 + threadIdx.x;
    if (idx >= 1024 * 768) return;
    int n = idx / 768, k = idx - n * 768;
    WT[idx] = f2b(k < 512 ? Wih[(size_t)n * 512 + k] : Whh[(size_t)n * 256 + (k - 512)]);
}

// pack f32 features -> bf16 rows padded to 160
__global__ __launch_bounds__(256) void prep_feat16_k(const float* __restrict__ F,
                                                     bf16u* __restrict__ O,
                                                     int rows, int K)
{
    int idx = blockIdx.x * 256 + threadIdx.x;
    if (idx >= rows * 160) return;
    int r = idx / 160, c = idx - r * 160;
    O[idx] = (c < K) ? f2b(F[(size_t)r * K + c]) : (bf16u)0;
}

// ---------------- small kernels ----------------
__global__ __launch_bounds__(256) void gather6_bf16_k(const bf16u* __restrict__ msg,
                                                      const int* __restrict__ a2b,
                                                      bf16u* __restrict__ outb)
{
    int idx = blockIdx.x * 256 + threadIdx.x;
    if (idx >= N_ATOMS * (H / 8)) return;
    int na = idx >> 5, c = idx & 31;
    const int* nb = a2b + (size_t)na * MAX_NB;
    float s[8] = {0.f, 0.f, 0.f, 0.f, 0.f, 0.f, 0.f, 0.f};
    #pragma unroll
    for (int j = 0; j < MAX_NB; ++j) {
        uint4 u = *(const uint4*)(msg + (size_t)nb[j] * H + c * 8);
        s[0] += b2f((bf16u)(u.x & 0xFFFFu)); s[1] += b2f((bf16u)(u.x >> 16));
        s[2] += b2f((bf16u)(u.y & 0xFFFFu)); s[3] += b2f((bf16u)(u.y >> 16));
        s[4] += b2f((bf16u)(u.z & 0xFFFFu)); s[5] += b2f((bf16u)(u.z >> 16));
        s[6] += b2f((bf16u)(u.w & 0xFFFFu)); s[7] += b2f((bf16u)(u.w >> 16));
    }
    uint4 o;
    o.x = (unsigned int)f2b(s[0]) | ((unsigned int)f2b(s[1]) << 16);
    o.y = (unsigned int)f2b(s[2]) | ((unsigned int)f2b(s[3]) << 16);
    o.z = (unsigned int)f2b(s[4]) | ((unsigned int)f2b(s[5]) << 16);
    o.w = (unsigned int)f2b(s[6]) | ((unsigned int)f2b(s[7]) << 16);
    *(uint4*)(outb + (size_t)na * H + c * 8) = o;
}

__global__ __launch_bounds__(256) void zero_f32_k(float* __restrict__ p, int n)
{
    int idx = blockIdx.x * 256 + threadIdx.x;
    if (idx < n) p[idx] = 0.f;
}

__device__ __forceinline__ float sigm(float x) { return 1.f / (1.f + expf(-x)); }

__global__ __launch_bounds__(256) void lstm_pw_k(const float* __restrict__ gates,
                                                 float* __restrict__ h,
                                                 float* __restrict__ c, int M)
{
    int idx = blockIdx.x * 256 + threadIdx.x;
    if (idx >= M * H) return;
    int m = idx >> 8, d = idx & 255;
    const float* g = gates + (size_t)m * (4 * H);
    float ig = sigm(g[d]);
    float fg = sigm(g[H + d]);
    float gg = tanhf(g[2 * H + d]);
    float og = sigm(g[3 * H + d]);
    float cn = fg * c[idx] + ig * gg;
    c[idx] = cn;
    h[idx] = og * tanhf(cn);
}

__global__ __launch_bounds__(256) void s2s_attn_k(const float* __restrict__ feat,
                                                  const float* __restrict__ h,
                                                  float* __restrict__ q_star, int Nn)
{
    int m = blockIdx.x;
    int t = threadIdx.x;
    int lane = t & 63, wave = t >> 6;
    __shared__ float sc[32];
    const float* f = feat + (size_t)m * Nn * H;
    const float* hm = h + (size_t)m * H;
    for (int n = wave; n < Nn; n += 4) {
        const float* fr = f + (size_t)n * H;
        float p = 0.f;
        #pragma unroll
        for (int u = 0; u < 4; ++u) p += fr[lane * 4 + u] * hm[lane * 4 + u];
        #pragma unroll
        for (int o = 32; o >= 1; o >>= 1) p += __shfl_xor(p, o);
        if (lane == 0) sc[n] = p;
    }
    __syncthreads();
    float mx = -1e30f;
    for (int n = 0; n < Nn; ++n) mx = fmaxf(mx, sc[n]);
    float ssum = 0.f, r = 0.f;
    for (int n = 0; n < Nn; ++n) {
        float a = expf(sc[n] - mx);
        ssum += a;
        r += a * f[(size_t)n * H + t];
    }
    r /= ssum;
    q_star[(size_t)m * (2 * H) + t] = hm[t];
    q_star[(size_t)m * (2 * H) + H + t] = r;
}

__global__ __launch_bounds__(256) void build_x_k(const float* __restrict__ P,
                                                 const float* __restrict__ Q,
                                                 const float* __restrict__ SO,
                                                 const float* __restrict__ b0,
                                                 float* __restrict__ X)
{
    int idx = blockIdx.x * 256 + threadIdx.x;
    if (idx >= B_RXN * S_STEPS * S_STEPS * H) return;
    int d  = idx & 255;
    int s2 = (idx >> 8) & 3;
    int s1 = (idx >> 10) & 3;
    int b  = idx >> 12;
    float v;
    if (s1 == s2) v = SO[((size_t)b * S_STEPS + s1) * H + d];
    else v = P[((size_t)b * S_STEPS + s1) * H + d] + Q[((size_t)b * S_STEPS + s2) * H + d] + b0[d];
    X[idx] = v;
}

// ---------------- launch ----------------
extern "C" void kernel_launch(void* const* d_in, const int* in_sizes, int n_in,
                              void* d_out, int out_size, void* d_ws, size_t ws_size,
                              hipStream_t stream)
{
    const float* f_atoms   = (const float*)d_in[0];
    const float* f_bonds   = (const float*)d_in[1];
    const int*   a2b       = (const int*)d_in[2];
    const int*   b2a       = (const int*)d_in[3];
    const int*   b2revb    = (const int*)d_in[4];
    const float* W_i       = (const float*)d_in[5];
    const float* W_h       = (const float*)d_in[6];
    const float* W_o       = (const float*)d_in[7];
    const float* b_o       = (const float*)d_in[8];
    const float* W_nn0     = (const float*)d_in[9];
    const float* b_nn0     = (const float*)d_in[10];
    const float* W_nn0s    = (const float*)d_in[11];
    const float* b_nn0s    = (const float*)d_in[12];
    const float* W_nn1     = (const float*)d_in[13];
    const float* b_nn1     = (const float*)d_in[14];
    const float* lstm_n_Wih = (const float*)d_in[15];
    const float* lstm_n_Whh = (const float*)d_in[16];
    const float* lstm_n_b   = (const float*)d_in[17];
    const float* node_cond_W = (const float*)d_in[18];
    const float* node_cond_b = (const float*)d_in[19];
    const float* lstm_g_Wih = (const float*)d_in[20];
    const float* lstm_g_Whh = (const float*)d_in[21];
    const float* lstm_g_b   = (const float*)d_in[22];
    const float* graph_cond_W = (const float*)d_in[23];
    const float* graph_cond_b = (const float*)d_in[24];
    float* out = (float*)d_out;

    // ---- workspace layout (~235 MB, same footprint as round 4) ----
    const size_t SZB = (size_t)NBP1 * H * sizeof(bf16u);    // 67,109,376 B
    char* base = (char*)d_ws;
    bf16u* INP  = (bf16u*)(base);                            // [NBP1,H]
    bf16u* MSG  = (bf16u*)(base + SZB);                      // [NBP1,H] (in-place updated)
    bf16u* MW   = (bf16u*)(base + 2 * SZB);                  // [NBP1,H] msg @ W_h
    bf16u* AMSG = (bf16u*)(base + 3 * SZB);                  // [N_ATOMS,H]
    bf16u* WT_I = (bf16u*)(base + 3 * SZB + 33554432);       // [256][160]
    bf16u* WT_H = (bf16u*)(base + 3 * SZB + 33636352);       // [256][256]
    bf16u* WT_O = (bf16u*)(base + 3 * SZB + 33767424);       // [256][416]
    // aliases (regions dead at time of use):
    bf16u* FB16 = MW;                                        // [NBP1][160] 42MB, before 1st MW
    bf16u* FA16 = MW;                                        // [N_ATOMS][160] 21MB, after last combine
    float* ATOMH = (float*)(base);                           // f32, alias INP (dead after combine 2)
    float* SMALL = (float*)(base + SZB);                     // f32 scratch, alias MSG (dead after final gather)
    float* GATES  = SMALL;
    float* HN     = SMALL + 2097152;
    float* CN     = SMALL + 2621440;
    float* QSTARN = SMALL + 3145728;
    float* MOL    = SMALL + 4194304;
    float* PP     = SMALL + 4718592;
    float* QQ     = SMALL + 5242880;
    float* SO     = SMALL + 5767168;
    float* XBUF   = SMALL + 6291456;
    float* STEPS  = SMALL + 8388608;
    float* HG     = SMALL + 8912896;
    float* CG     = SMALL + 9043968;
    float* QSTARG = SMALL + 9175040;
    float* GATESG = SMALL + 9437184;
    // mid-phase weights: in MW region after FA16 (MW+24MB..+28.6MB; dead zone)
    char* sm2 = base + 2 * SZB + 25165824;
    bf16u* WTG_N = (bf16u*)(sm2);
    bf16u* WTG_G = (bf16u*)(sm2 + 1572864);
    bf16u* WT_NC = (bf16u*)(sm2 + 3145728);
    bf16u* WT_P  = (bf16u*)(sm2 + 3407872);
    bf16u* WT_Q  = (bf16u*)(sm2 + 3538944);
    bf16u* WT_S  = (bf16u*)(sm2 + 3670016);
    bf16u* WT_N1 = (bf16u*)(sm2 + 3801088);
    bf16u* WT_GC = (bf16u*)(sm2 + 4325376);

    dim3 blk(256);
    const int MB_BOND = (NBP1 + 63) / 64;     // 2049
    const int MB_ATOM = N_ATOMS / 64;         // 1024
    const int G_GATH = (N_ATOMS * (H / 8) + 255) / 256;
    const int G_COMB = (NBP1 * 32 + 255) / 256;

    // 0. weight + input prep
    prep_wt_k<<<(256 * 160 + 255) / 256, blk, 0, stream>>>(W_i, WT_I, BOND_FDIM, 160);
    prep_wt_k<<<(256 * 256 + 255) / 256, blk, 0, stream>>>(W_h, WT_H, H, 256);
    prep_wto_k<<<(256 * 416 + 255) / 256, blk, 0, stream>>>(W_o, WT_O);
    prep_feat16_k<<<(int)(((size_t)NBP1 * 160 + 255) / 256), blk, 0, stream>>>(
        f_bonds, FB16, NBP1, BOND_FDIM);

    // 1. inp = FB16 @ W_i -> INP ; MSG = relu(inp)
    dense_gemm_k<0><<<MB_BOND, blk, 0, stream>>>(
        FB16, nullptr, WT_I, nullptr, nullptr, INP, MSG, NBP1);

    // 2. depth loop: MW = MSG @ W_h ; AP = gather6(MW) ; MSG = relu(INP + AP[b2a] - MW[b2revb])
    for (int d = 0; d < DEPTH - 1; ++d) {
        dense_gemm_k<1><<<MB_BOND, blk, 0, stream>>>(
            MSG, nullptr, WT_H, nullptr, nullptr, MW, nullptr, NBP1);
        gather6_bf16_k<<<G_GATH, blk, 0, stream>>>(MW, a2b, AMSG);
        combine_k<<<G_COMB, blk, 0, stream>>>(INP, AMSG, MW, b2a, b2revb, MSG);
    }

    // 3. nei = gather6(final MSG)
    gather6_bf16_k<<<G_GATH, blk, 0, stream>>>(MSG, a2b, AMSG);

    // 3b. packed f_atoms + mid-phase weight prep (MW region dead)
    prep_feat16_k<<<(N_ATOMS * 160 + 255) / 256, blk, 0, stream>>>(
        f_atoms, FA16, N_ATOMS, ATOM_FDIM);
    prep_wt_gates_k<<<(1024 * 768 + 255) / 256, blk, 0, stream>>>(lstm_n_Wih, lstm_n_Whh, WTG_N);
    prep_wt_gates_k<<<(1024 * 768 + 255) / 256, blk, 0, stream>>>(lstm_g_Wih, lstm_g_Whh, WTG_G);
    prep_wt_t_k<<<(256 * 512 + 255) / 256, blk, 0, stream>>>(node_cond_W, WT_NC, 512);
    prep_wt_t_k<<<(256 * 256 + 255) / 256, blk, 0, stream>>>(W_nn0, WT_P, 256);
    prep_wt_t_k<<<(256 * 256 + 255) / 256, blk, 0, stream>>>(W_nn0 + 256 * 256, WT_Q, 256);
    prep_wt_t_k<<<(256 * 256 + 255) / 256, blk, 0, stream>>>(W_nn0s, WT_S, 256);
    prep_wt_t_k<<<(256 * 1024 + 255) / 256, blk, 0, stream>>>(W_nn1, WT_N1, 1024);
    prep_wt_t_k<<<(256 * 512 + 255) / 256, blk, 0, stream>>>(graph_cond_W, WT_GC, 512);

    // 4. atom_h = relu([f_atoms, nei] @ W_o + b_o) -> ATOMH f32 (aliases dead INP)
    dense_gemm_k<2><<<MB_ATOM, blk, 0, stream>>>(
        FA16, AMSG, WT_O, b_o, ATOMH, nullptr, nullptr, N_ATOMS);

    // 5. node Set2Set over [2048, 32, 256]
    zero_f32_k<<<(2097152 + 255) / 256, blk, 0, stream>>>(HN, 2097152);  // HN,CN,QSTARN
    for (int it = 0; it < N_ITERS; ++it) {
        mfma_lin_k<true><<<dim3(N_MOLS / 64, 4), blk, 0, stream>>>(
            QSTARN, 2 * H, 2 * H, HN, H, WTG_N, lstm_n_b, GATES, 4 * H, 3 * H);
        lstm_pw_k<<<(N_MOLS * H) / 256, blk, 0, stream>>>(GATES, HN, CN, N_MOLS);
        s2s_attn_k<<<N_MOLS, blk, 0, stream>>>(ATOMH, HN, QSTARN, ATOMS_PER_MOL);
    }
    mfma_lin_k<true><<<dim3(N_MOLS / 64, 1), blk, 0, stream>>>(
        QSTARN, 2 * H, 2 * H, QSTARN, 2 * H, WT_NC, node_cond_b, MOL, H, 2 * H);

    // 6. NN attention over steps
    mfma_lin_k<false><<<dim3(N_MOLS / 64, 1), blk, 0, stream>>>(
        MOL, H, H, MOL, H, WT_P, nullptr, PP, H, H);
    mfma_lin_k<false><<<dim3(N_MOLS / 64, 1), blk, 0, stream>>>(
        MOL, H, H, MOL, H, WT_Q, nullptr, QQ, H, H);
    mfma_lin_k<true><<<dim3(N_MOLS / 64, 1), blk, 0, stream>>>(
        MOL, H, H, MOL, H, WT_S, b_nn0s, SO, H, H);
    build_x_k<<<(B_RXN * 16 * H) / 256, blk, 0, stream>>>(PP, QQ, SO, b_nn0, XBUF);
    mfma_lin_k<true><<<dim3(N_MOLS / 64, 1), blk, 0, stream>>>(
        XBUF, S_STEPS * H, S_STEPS * H, XBUF, S_STEPS * H, WT_N1, b_nn1, STEPS, H, S_STEPS * H);

    // 7. graph Set2Set over [512, 4, 256]
    zero_f32_k<<<(524288 + 255) / 256, blk, 0, stream>>>(HG, 524288);    // HG,CG,QSTARG
    for (int it = 0; it < N_ITERS; ++it) {
        mfma_lin_k<true><<<dim3(B_RXN / 64, 4), blk, 0, stream>>>(
            QSTARG, 2 * H, 2 * H, HG, H, WTG_G, lstm_g_b, GATESG, 4 * H, 3 * H);
        lstm_pw_k<<<(B_RXN * H) / 256, blk, 0, stream>>>(GATESG, HG, CG, B_RXN);
        s2s_attn_k<<<B_RXN, blk, 0, stream>>>(STEPS, HG, QSTARG, S_STEPS);
    }

    // 8. out
    mfma_lin_k<true><<<dim3(B_RXN / 64, 1), blk, 0, stream>>>(
        QSTARG, 2 * H, 2 * H, QSTARG, 2 * H, WT_GC, graph_cond_b, out, H, 2 * H);
}

// Round 9
// 739.826 us; speedup vs baseline: 1.7666x; 1.4316x over previous
//
#include <hip/hip_runtime.h>
#include <math.h>

// ---------------- problem constants ----------------
#define H 256
#define S_STEPS 4
#define B_RXN 512
#define N_MOLS 2048          // B*S
#define ATOMS_PER_MOL 32
#define N_ATOMS 65536        // N_MOLS*32
#define N_BONDS 131072
#define NBP1 131073          // N_BONDS+1
#define MAX_NB 6
#define ATOM_FDIM 133
#define BOND_FDIM 147
#define DEPTH 3
#define N_ITERS 3

typedef unsigned short bf16u;
typedef __attribute__((ext_vector_type(8))) short short8v;  // 8 bf16 = 4 VGPR
typedef __attribute__((ext_vector_type(4))) float f32x4;

__device__ __forceinline__ float b2f(bf16u u) {
    union { unsigned int i; float f; } c; c.i = ((unsigned int)u) << 16; return c.f;
}
__device__ __forceinline__ bf16u f2b(float f) {
    union { float f; unsigned int i; } c; c.f = f;
    unsigned int i = c.i;
    return (bf16u)((i + 0x7FFFu + ((i >> 16) & 1u)) >> 16);   // RNE
}

// ============ dense MFMA GEMM (bond/atom phase) — unchanged (round-8 proven) ============
template<int MODE>
__global__ __launch_bounds__(256) void dense_gemm_k(
    const bf16u* __restrict__ A1,
    const bf16u* __restrict__ A2,     // MODE2 only
    const bf16u* __restrict__ WT,     // [256][KP] bf16
    const float* __restrict__ bias,   // MODE2 only
    float* __restrict__ outf,
    bf16u* __restrict__ outb, bf16u* __restrict__ outb2,
    int M)
{
    constexpr int KP = (MODE == 0) ? 160 : ((MODE == 1) ? 256 : 416);
    __shared__ bf16u As[64][40];
    __shared__ bf16u Bs[256][40];

    const int tid = threadIdx.x;
    const int lane = tid & 63, w = tid >> 6;
    const int m0 = blockIdx.x * 64;
    const int ar = tid >> 2, q8 = (tid & 3) * 8;
    const int arow = m0 + ar;
    const bool rok = arow < M;
    const int lr = lane & 15, lk = (lane >> 4) * 8;
    const uint4 z4 = {0u, 0u, 0u, 0u};

    f32x4 acc[4][4];
    const f32x4 zf = {0.f, 0.f, 0.f, 0.f};
    #pragma unroll
    for (int i = 0; i < 4; ++i)
        #pragma unroll
        for (int j = 0; j < 4; ++j) acc[i][j] = zf;

    for (int k0 = 0; k0 < KP; k0 += 32) {
        const int kc = k0 + q8;
        uint4 va;
        if (MODE == 2) {
            va = (kc < 160) ? *(const uint4*)(A1 + (size_t)arow * 160 + kc)
                            : *(const uint4*)(A2 + (size_t)arow * 256 + (kc - 160));
        } else {
            constexpr int LDA = (MODE == 0) ? 160 : 256;
            va = rok ? *(const uint4*)(A1 + (size_t)arow * LDA + kc) : z4;
        }
        *(uint4*)&As[ar][q8] = va;
        {
            const bf16u* bp = WT + (size_t)tid * KP + k0;
            uint4 q0 = *(const uint4*)(bp);
            uint4 q1 = *(const uint4*)(bp + 8);
            uint4 q2 = *(const uint4*)(bp + 16);
            uint4 q3 = *(const uint4*)(bp + 24);
            *(uint4*)&Bs[tid][0]  = q0;
            *(uint4*)&Bs[tid][8]  = q1;
            *(uint4*)&Bs[tid][16] = q2;
            *(uint4*)&Bs[tid][24] = q3;
        }
        __syncthreads();

        short8v a[4], b[4];
        #pragma unroll
        for (int mf = 0; mf < 4; ++mf)
            a[mf] = *(const short8v*)&As[mf * 16 + lr][lk];
        #pragma unroll
        for (int nf = 0; nf < 4; ++nf)
            b[nf] = *(const short8v*)&Bs[w * 64 + nf * 16 + lr][lk];
        #pragma unroll
        for (int mf = 0; mf < 4; ++mf)
            #pragma unroll
            for (int nf = 0; nf < 4; ++nf)
                acc[mf][nf] = __builtin_amdgcn_mfma_f32_16x16x32_bf16(
                    a[mf], b[nf], acc[mf][nf], 0, 0, 0);
        __syncthreads();
    }

    const int rbase = (lane >> 4) * 4;
    #pragma unroll
    for (int mf = 0; mf < 4; ++mf) {
        #pragma unroll
        for (int nf = 0; nf < 4; ++nf) {
            const int col = w * 64 + nf * 16 + lr;
            #pragma unroll
            for (int r = 0; r < 4; ++r) {
                const int row = m0 + mf * 16 + rbase + r;
                if (row >= M) continue;
                float v = acc[mf][nf][r];
                const size_t off = (size_t)row * H + col;
                if (MODE == 0) {
                    outb[off] = f2b(v);
                    outb2[off] = f2b(fmaxf(v, 0.f));
                } else if (MODE == 1) {
                    outb[off] = f2b(v);
                } else {
                    v += bias[col];
                    outf[off] = fmaxf(v, 0.f);
                }
            }
        }
    }
}

// ---- combine: msg[b] = relu(inp[b] + AP[b2a[b]] - MW[b2revb[b]]), row 0 = 0 ----
__global__ __launch_bounds__(256) void combine_k(
    const bf16u* __restrict__ inp, const bf16u* __restrict__ AP,
    const bf16u* __restrict__ MW,
    const int* __restrict__ b2a, const int* __restrict__ b2revb,
    bf16u* __restrict__ msg)
{
    int idx = blockIdx.x * 256 + threadIdx.x;
    if (idx >= NBP1 * 32) return;
    int b = idx >> 5, c = (idx & 31) * 8;
    bf16u* op = msg + (size_t)b * H + c;
    if (b == 0) {
        *(uint4*)op = make_uint4(0u, 0u, 0u, 0u);
        return;
    }
    int a = b2a[b], rb = b2revb[b];
    uint4 ui = *(const uint4*)(inp + (size_t)b * H + c);
    uint4 up = *(const uint4*)(AP + (size_t)a * H + c);
    uint4 um = *(const uint4*)(MW + (size_t)rb * H + c);
    uint4 o;
    unsigned int* pi = &ui.x; unsigned int* pp = &up.x;
    unsigned int* pm = &um.x; unsigned int* po = &o.x;
    #pragma unroll
    for (int t = 0; t < 4; ++t) {
        float lo = b2f((bf16u)(pi[t] & 0xFFFFu)) + b2f((bf16u)(pp[t] & 0xFFFFu))
                 - b2f((bf16u)(pm[t] & 0xFFFFu));
        float hi = b2f((bf16u)(pi[t] >> 16)) + b2f((bf16u)(pp[t] >> 16))
                 - b2f((bf16u)(pm[t] >> 16));
        lo = fmaxf(lo, 0.f); hi = fmaxf(hi, 0.f);
        po[t] = (unsigned int)f2b(lo) | ((unsigned int)f2b(hi) << 16);
    }
    *(uint4*)op = o;
}

// ============ mid-phase MFMA linear, BM=64 x BN=64, CU-filling grid ============
// C[m0+.., col0+..] = A[M,K] @ WT^T (+bias). A f32; dual-A fused-K split at KA1
// (KA1 % 32 == 0 -> per-k-step-uniform source, unconditional float4 loads).
// WT [Ntot][ldw] bf16. grid = (M/64, Ntot/64). Wave w: rows w*16..+15, all 64 cols.
template<bool BIAS>
__global__ __launch_bounds__(256) void lin64_k(
    const float* __restrict__ A1, int lda1, int KA1,
    const float* __restrict__ A2, int lda2,
    const bf16u* __restrict__ WT, int ldw,
    const float* __restrict__ bias,
    float* __restrict__ C, int ldc, int K)
{
    __shared__ bf16u As[64][40];
    __shared__ bf16u Bs[64][40];
    const int tid = threadIdx.x;
    const int lane = tid & 63, w = tid >> 6;
    const int m0 = blockIdx.x * 64;
    const int col0 = blockIdx.y * 64;
    const int ar = tid >> 2, kq8 = (tid & 3) * 8;
    const int lr = lane & 15, lk = (lane >> 4) * 8;

    f32x4 acc[4];
    const f32x4 zf = {0.f, 0.f, 0.f, 0.f};
    #pragma unroll
    for (int j = 0; j < 4; ++j) acc[j] = zf;

    for (int k0 = 0; k0 < K; k0 += 32) {
        // A: rows m0..+63, cols k0..+31; source uniform per k-step
        const float* src = (k0 < KA1)
            ? (A1 + (size_t)(m0 + ar) * lda1 + k0 + kq8)
            : (A2 + (size_t)(m0 + ar) * lda2 + (k0 - KA1) + kq8);
        float4 f0 = *(const float4*)src;
        float4 f1 = *(const float4*)(src + 4);
        ushort4 s0, s1;
        s0.x = f2b(f0.x); s0.y = f2b(f0.y); s0.z = f2b(f0.z); s0.w = f2b(f0.w);
        s1.x = f2b(f1.x); s1.y = f2b(f1.y); s1.z = f2b(f1.z); s1.w = f2b(f1.w);
        *(ushort4*)&As[ar][kq8] = s0;
        *(ushort4*)&As[ar][kq8 + 4] = s1;
        // B: WT rows col0..+63, cols k0..+31
        *(uint4*)&Bs[ar][kq8] = *(const uint4*)(WT + (size_t)(col0 + ar) * ldw + k0 + kq8);
        __syncthreads();

        short8v a = *(const short8v*)&As[w * 16 + lr][lk];
        short8v b[4];
        #pragma unroll
        for (int nf = 0; nf < 4; ++nf)
            b[nf] = *(const short8v*)&Bs[nf * 16 + lr][lk];
        #pragma unroll
        for (int nf = 0; nf < 4; ++nf)
            acc[nf] = __builtin_amdgcn_mfma_f32_16x16x32_bf16(a, b[nf], acc[nf], 0, 0, 0);
        __syncthreads();
    }

    const int rbase = (lane >> 4) * 4;
    #pragma unroll
    for (int nf = 0; nf < 4; ++nf) {
        const int col = col0 + nf * 16 + lr;
        #pragma unroll
        for (int r = 0; r < 4; ++r) {
            const int row = m0 + w * 16 + rbase + r;
            float v = acc[nf][r];
            if (BIAS) v += bias[col];
            C[(size_t)row * ldc + col] = v;
        }
    }
}

// ---------------- prep kernels ----------------
__global__ __launch_bounds__(256) void prep_wt_k(const float* __restrict__ W,
                                                 bf16u* __restrict__ WT, int K, int KP)
{
    int idx = blockIdx.x * 256 + threadIdx.x;
    if (idx >= 256 * KP) return;
    int n = idx / KP, k = idx - n * KP;
    WT[idx] = (k < K) ? f2b(W[(size_t)k * H + n]) : (bf16u)0;
}

__global__ __launch_bounds__(256) void prep_wto_k(const float* __restrict__ Wo,
                                                  bf16u* __restrict__ WT)
{
    int idx = blockIdx.x * 256 + threadIdx.x;
    if (idx >= 256 * 416) return;
    int n = idx / 416, k = idx - n * 416;
    float v = 0.f;
    if (k < ATOM_FDIM) v = Wo[(size_t)k * H + n];
    else if (k >= 160) v = Wo[(size_t)(ATOM_FDIM + k - 160) * H + n];
    WT[idx] = f2b(v);
}

__global__ __launch_bounds__(256) void prep_wt_t_k(const float* __restrict__ W,
                                                   bf16u* __restrict__ WT, int K)
{
    int idx = blockIdx.x * 256 + threadIdx.x;
    if (idx >= 256 * K) return;
    int n = idx / K, k = idx - n * K;
    WT[idx] = f2b(W[(size_t)k * 256 + n]);
}

__global__ __launch_bounds__(256) void prep_wt_gates_k(const float* __restrict__ Wih,
                                                       const float* __restrict__ Whh,
                                                       bf16u* __restrict__ WT)
{
    int idx = blockIdx.x * 256 + threadIdx.x;
    if (idx >= 1024 * 768) return;
    int n = idx / 768, k = idx - n * 768;
    WT[idx] = f2b(k < 512 ? Wih[(size_t)n * 512 + k] : Whh[(size_t)n * 256 + (k - 512)]);
}

// fused PQS: WT [768][256]; rows 0-255: W_nn0 top; 256-511: W_nn0 bottom; 512-767: W_nn0s
__global__ __launch_bounds__(256) void prep_wt_pqs_k(const float* __restrict__ Wnn0,
                                                     const float* __restrict__ Wnn0s,
                                                     bf16u* __restrict__ WT,
                                                     float* __restrict__ bias_pqs,
                                                     const float* __restrict__ b_nn0s)
{
    int idx = blockIdx.x * 256 + threadIdx.x;
    if (idx < 768) bias_pqs[idx] = (idx < 512) ? 0.f : b_nn0s[idx - 512];
    if (idx >= 768 * 256) return;
    int n = idx / 256, k = idx - n * 256;
    float v;
    if (n < 256)      v = Wnn0[(size_t)k * 256 + n];
    else if (n < 512) v = Wnn0[(size_t)(256 + k) * 256 + (n - 256)];
    else              v = Wnn0s[(size_t)k * 256 + (n - 512)];
    WT[idx] = f2b(v);
}

// pack f32 features -> bf16 rows padded to 160
__global__ __launch_bounds__(256) void prep_feat16_k(const float* __restrict__ F,
                                                     bf16u* __restrict__ O,
                                                     int rows, int K)
{
    int idx = blockIdx.x * 256 + threadIdx.x;
    if (idx >= rows * 160) return;
    int r = idx / 160, c = idx - r * 160;
    O[idx] = (c < K) ? f2b(F[(size_t)r * K + c]) : (bf16u)0;
}

// ---------------- small kernels ----------------
__global__ __launch_bounds__(256) void gather6_bf16_k(const bf16u* __restrict__ msg,
                                                      const int* __restrict__ a2b,
                                                      bf16u* __restrict__ outb)
{
    int idx = blockIdx.x * 256 + threadIdx.x;
    if (idx >= N_ATOMS * (H / 8)) return;
    int na = idx >> 5, c = idx & 31;
    const int* nb = a2b + (size_t)na * MAX_NB;
    float s[8] = {0.f, 0.f, 0.f, 0.f, 0.f, 0.f, 0.f, 0.f};
    #pragma unroll
    for (int j = 0; j < MAX_NB; ++j) {
        uint4 u = *(const uint4*)(msg + (size_t)nb[j] * H + c * 8);
        s[0] += b2f((bf16u)(u.x & 0xFFFFu)); s[1] += b2f((bf16u)(u.x >> 16));
        s[2] += b2f((bf16u)(u.y & 0xFFFFu)); s[3] += b2f((bf16u)(u.y >> 16));
        s[4] += b2f((bf16u)(u.z & 0xFFFFu)); s[5] += b2f((bf16u)(u.z >> 16));
        s[6] += b2f((bf16u)(u.w & 0xFFFFu)); s[7] += b2f((bf16u)(u.w >> 16));
    }
    uint4 o;
    o.x = (unsigned int)f2b(s[0]) | ((unsigned int)f2b(s[1]) << 16);
    o.y = (unsigned int)f2b(s[2]) | ((unsigned int)f2b(s[3]) << 16);
    o.z = (unsigned int)f2b(s[4]) | ((unsigned int)f2b(s[5]) << 16);
    o.w = (unsigned int)f2b(s[6]) | ((unsigned int)f2b(s[7]) << 16);
    *(uint4*)(outb + (size_t)na * H + c * 8) = o;
}

__global__ __launch_bounds__(256) void zero_f32_k(float* __restrict__ p, int n)
{
    int idx = blockIdx.x * 256 + threadIdx.x;
    if (idx < n) p[idx] = 0.f;
}

__device__ __forceinline__ float sigm(float x) { return 1.f / (1.f + expf(-x)); }

__global__ __launch_bounds__(256) void lstm_pw_k(const float* __restrict__ gates,
                                                 float* __restrict__ h,
                                                 float* __restrict__ c, int M)
{
    int idx = blockIdx.x * 256 + threadIdx.x;
    if (idx >= M * H) return;
    int m = idx >> 8, d = idx & 255;
    const float* g = gates + (size_t)m * (4 * H);
    float ig = sigm(g[d]);
    float fg = sigm(g[H + d]);
    float gg = tanhf(g[2 * H + d]);
    float og = sigm(g[3 * H + d]);
    float cn = fg * c[idx] + ig * gg;
    c[idx] = cn;
    h[idx] = og * tanhf(cn);
}

__global__ __launch_bounds__(256) void s2s_attn_k(const float* __restrict__ feat,
                                                  const float* __restrict__ h,
                                                  float* __restrict__ q_star, int Nn)
{
    int m = blockIdx.x;
    int t = threadIdx.x;
    int lane = t & 63, wave = t >> 6;
    __shared__ float sc[32];
    const float* f = feat + (size_t)m * Nn * H;
    const float* hm = h + (size_t)m * H;
    for (int n = wave; n < Nn; n += 4) {
        const float* fr = f + (size_t)n * H;
        float p = 0.f;
        #pragma unroll
        for (int u = 0; u < 4; ++u) p += fr[lane * 4 + u] * hm[lane * 4 + u];
        #pragma unroll
        for (int o = 32; o >= 1; o >>= 1) p += __shfl_xor(p, o);
        if (lane == 0) sc[n] = p;
    }
    __syncthreads();
    float mx = -1e30f;
    for (int n = 0; n < Nn; ++n) mx = fmaxf(mx, sc[n]);
    float ssum = 0.f, r = 0.f;
    for (int n = 0; n < Nn; ++n) {
        float a = expf(sc[n] - mx);
        ssum += a;
        r += a * f[(size_t)n * H + t];
    }
    r /= ssum;
    q_star[(size_t)m * (2 * H) + t] = hm[t];
    q_star[(size_t)m * (2 * H) + H + t] = r;
}

// X[b,s1,s2,:] from packed PQS [2048][768]: P = +0, Q = +256, SO = +512
__global__ __launch_bounds__(256) void build_x_k(const float* __restrict__ PQS,
                                                 const float* __restrict__ b0,
                                                 float* __restrict__ X)
{
    int idx = blockIdx.x * 256 + threadIdx.x;
    if (idx >= B_RXN * S_STEPS * S_STEPS * H) return;
    int d  = idx & 255;
    int s2 = (idx >> 8) & 3;
    int s1 = (idx >> 10) & 3;
    int b  = idx >> 12;
    float v;
    if (s1 == s2) v = PQS[((size_t)(b * S_STEPS + s1)) * 768 + 512 + d];
    else v = PQS[((size_t)(b * S_STEPS + s1)) * 768 + d]
           + PQS[((size_t)(b * S_STEPS + s2)) * 768 + 256 + d] + b0[d];
    X[idx] = v;
}

// ---------------- launch ----------------
extern "C" void kernel_launch(void* const* d_in, const int* in_sizes, int n_in,
                              void* d_out, int out_size, void* d_ws, size_t ws_size,
                              hipStream_t stream)
{
    const float* f_atoms   = (const float*)d_in[0];
    const float* f_bonds   = (const float*)d_in[1];
    const int*   a2b       = (const int*)d_in[2];
    const int*   b2a       = (const int*)d_in[3];
    const int*   b2revb    = (const int*)d_in[4];
    const float* W_i       = (const float*)d_in[5];
    const float* W_h       = (const float*)d_in[6];
    const float* W_o       = (const float*)d_in[7];
    const float* b_o       = (const float*)d_in[8];
    const float* W_nn0     = (const float*)d_in[9];
    const float* b_nn0     = (const float*)d_in[10];
    const float* W_nn0s    = (const float*)d_in[11];
    const float* b_nn0s    = (const float*)d_in[12];
    const float* W_nn1     = (const float*)d_in[13];
    const float* b_nn1     = (const float*)d_in[14];
    const float* lstm_n_Wih = (const float*)d_in[15];
    const float* lstm_n_Whh = (const float*)d_in[16];
    const float* lstm_n_b   = (const float*)d_in[17];
    const float* node_cond_W = (const float*)d_in[18];
    const float* node_cond_b = (const float*)d_in[19];
    const float* lstm_g_Wih = (const float*)d_in[20];
    const float* lstm_g_Whh = (const float*)d_in[21];
    const float* lstm_g_b   = (const float*)d_in[22];
    const float* graph_cond_W = (const float*)d_in[23];
    const float* graph_cond_b = (const float*)d_in[24];
    float* out = (float*)d_out;

    // ---- workspace layout (~235 MB) ----
    const size_t SZB = (size_t)NBP1 * H * sizeof(bf16u);    // 67,109,376 B
    char* base = (char*)d_ws;
    bf16u* INP  = (bf16u*)(base);                            // [NBP1,H]
    bf16u* MSG  = (bf16u*)(base + SZB);                      // [NBP1,H] (in-place updated)
    bf16u* MW   = (bf16u*)(base + 2 * SZB);                  // [NBP1,H] msg @ W_h
    bf16u* AMSG = (bf16u*)(base + 3 * SZB);                  // [N_ATOMS,H]
    bf16u* WT_I = (bf16u*)(base + 3 * SZB + 33554432);       // [256][160]
    bf16u* WT_H = (bf16u*)(base + 3 * SZB + 33636352);       // [256][256]
    bf16u* WT_O = (bf16u*)(base + 3 * SZB + 33767424);       // [256][416]
    // aliases (regions dead at time of use):
    bf16u* FB16 = MW;                                        // [NBP1][160], before 1st MW
    bf16u* FA16 = MW;                                        // [N_ATOMS][160], after last combine
    float* ATOMH = (float*)(base);                           // f32, alias INP
    float* SMALL = (float*)(base + SZB);                     // f32 scratch, alias MSG
    float* GATES  = SMALL;                                   // [2048,1024]
    float* HN     = SMALL + 2097152;                         // [2048,256]
    float* CN     = SMALL + 2621440;                         // [2048,256]
    float* QSTARN = SMALL + 3145728;                         // [2048,512]
    float* MOL    = SMALL + 4194304;                         // [2048,256]
    float* PQS    = SMALL + 4718592;                         // [2048,768]
    float* XBUF   = SMALL + 6291456;                         // [8192,256]
    float* STEPS  = SMALL + 8388608;                         // [2048,256]
    float* HG     = SMALL + 8912896;                         // [512,256]
    float* CG     = SMALL + 9043968;                         // [512,256]
    float* QSTARG = SMALL + 9175040;                         // [512,512]
    float* GATESG = SMALL + 9437184;                         // [512,1024]
    // mid-phase weights in MW dead zone (+24 MB)
    char* sm2 = base + 2 * SZB + 25165824;
    bf16u* WTG_N   = (bf16u*)(sm2);                  // [1024][768]
    bf16u* WTG_G   = (bf16u*)(sm2 + 1572864);        // [1024][768]
    bf16u* WT_NC   = (bf16u*)(sm2 + 3145728);        // [256][512]
    bf16u* WT_PQS  = (bf16u*)(sm2 + 3407872);        // [768][256]
    bf16u* WT_N1   = (bf16u*)(sm2 + 3801088);        // [256][1024]
    bf16u* WT_GC   = (bf16u*)(sm2 + 4325376);        // [256][512]
    float* BIAS_PQS = (float*)(sm2 + 4587520);       // [768]

    dim3 blk(256);
    const int MB_BOND = (NBP1 + 63) / 64;     // 2049
    const int MB_ATOM = N_ATOMS / 64;         // 1024
    const int G_GATH = (N_ATOMS * (H / 8) + 255) / 256;
    const int G_COMB = (NBP1 * 32 + 255) / 256;

    // 0. weight + input prep
    prep_wt_k<<<(256 * 160 + 255) / 256, blk, 0, stream>>>(W_i, WT_I, BOND_FDIM, 160);
    prep_wt_k<<<(256 * 256 + 255) / 256, blk, 0, stream>>>(W_h, WT_H, H, 256);
    prep_wto_k<<<(256 * 416 + 255) / 256, blk, 0, stream>>>(W_o, WT_O);
    prep_feat16_k<<<(int)(((size_t)NBP1 * 160 + 255) / 256), blk, 0, stream>>>(
        f_bonds, FB16, NBP1, BOND_FDIM);

    // 1. inp = FB16 @ W_i -> INP ; MSG = relu(inp)
    dense_gemm_k<0><<<MB_BOND, blk, 0, stream>>>(
        FB16, nullptr, WT_I, nullptr, nullptr, INP, MSG, NBP1);

    // 2. depth loop: MW = MSG @ W_h ; AP = gather6(MW) ; MSG = relu(INP + AP[b2a] - MW[b2revb])
    for (int d = 0; d < DEPTH - 1; ++d) {
        dense_gemm_k<1><<<MB_BOND, blk, 0, stream>>>(
            MSG, nullptr, WT_H, nullptr, nullptr, MW, nullptr, NBP1);
        gather6_bf16_k<<<G_GATH, blk, 0, stream>>>(MW, a2b, AMSG);
        combine_k<<<G_COMB, blk, 0, stream>>>(INP, AMSG, MW, b2a, b2revb, MSG);
    }

    // 3. nei = gather6(final MSG)
    gather6_bf16_k<<<G_GATH, blk, 0, stream>>>(MSG, a2b, AMSG);

    // 3b. packed f_atoms + mid-phase weight prep (MW region dead)
    prep_feat16_k<<<(N_ATOMS * 160 + 255) / 256, blk, 0, stream>>>(
        f_atoms, FA16, N_ATOMS, ATOM_FDIM);
    prep_wt_gates_k<<<(1024 * 768 + 255) / 256, blk, 0, stream>>>(lstm_n_Wih, lstm_n_Whh, WTG_N);
    prep_wt_gates_k<<<(1024 * 768 + 255) / 256, blk, 0, stream>>>(lstm_g_Wih, lstm_g_Whh, WTG_G);
    prep_wt_t_k<<<(256 * 512 + 255) / 256, blk, 0, stream>>>(node_cond_W, WT_NC, 512);
    prep_wt_pqs_k<<<(768 * 256 + 255) / 256, blk, 0, stream>>>(W_nn0, W_nn0s, WT_PQS, BIAS_PQS, b_nn0s);
    prep_wt_t_k<<<(256 * 1024 + 255) / 256, blk, 0, stream>>>(W_nn1, WT_N1, 1024);
    prep_wt_t_k<<<(256 * 512 + 255) / 256, blk, 0, stream>>>(graph_cond_W, WT_GC, 512);

    // 4. atom_h = relu([f_atoms, nei] @ W_o + b_o) -> ATOMH f32
    dense_gemm_k<2><<<MB_ATOM, blk, 0, stream>>>(
        FA16, AMSG, WT_O, b_o, ATOMH, nullptr, nullptr, N_ATOMS);

    // 5. node Set2Set over [2048, 32, 256]
    zero_f32_k<<<(2097152 + 255) / 256, blk, 0, stream>>>(HN, 2097152);  // HN,CN,QSTARN
    for (int it = 0; it < N_ITERS; ++it) {
        lin64_k<true><<<dim3(N_MOLS / 64, 16), blk, 0, stream>>>(
            QSTARN, 2 * H, 2 * H, HN, H, WTG_N, 3 * H, lstm_n_b, GATES, 4 * H, 3 * H);
        lstm_pw_k<<<(N_MOLS * H) / 256, blk, 0, stream>>>(GATES, HN, CN, N_MOLS);
        s2s_attn_k<<<N_MOLS, blk, 0, stream>>>(ATOMH, HN, QSTARN, ATOMS_PER_MOL);
    }
    lin64_k<true><<<dim3(N_MOLS / 64, 4), blk, 0, stream>>>(
        QSTARN, 2 * H, 2 * H, QSTARN, 2 * H, WT_NC, 2 * H, node_cond_b, MOL, H, 2 * H);

    // 6. NN attention over steps (fused P|Q|SO GEMM)
    lin64_k<true><<<dim3(N_MOLS / 64, 12), blk, 0, stream>>>(
        MOL, H, H, MOL, H, WT_PQS, H, BIAS_PQS, PQS, 3 * H, H);
    build_x_k<<<(B_RXN * 16 * H) / 256, blk, 0, stream>>>(PQS, b_nn0, XBUF);
    lin64_k<true><<<dim3(N_MOLS / 64, 4), blk, 0, stream>>>(
        XBUF, S_STEPS * H, S_STEPS * H, XBUF, S_STEPS * H, WT_N1, S_STEPS * H, b_nn1,
        STEPS, H, S_STEPS * H);

    // 7. graph Set2Set over [512, 4, 256]
    zero_f32_k<<<(524288 + 255) / 256, blk, 0, stream>>>(HG, 524288);    // HG,CG,QSTARG
    for (int it = 0; it < N_ITERS; ++it) {
        lin64_k<true><<<dim3(B_RXN / 64, 16), blk, 0, stream>>>(
            QSTARG, 2 * H, 2 * H, HG, H, WTG_G, 3 * H, lstm_g_b, GATESG, 4 * H, 3 * H);
        lstm_pw_k<<<(B_RXN * H) / 256, blk, 0, stream>>>(GATESG, HG, CG, B_RXN);
        s2s_attn_k<<<B_RXN, blk, 0, stream>>>(STEPS, HG, QSTARG, S_STEPS);
    }

    // 8. out
    lin64_k<true><<<dim3(B_RXN / 64, 4), blk, 0, stream>>>(
        QSTARG, 2 * H, 2 * H, QSTARG, 2 * H, WT_GC, 2 * H, graph_cond_b, out, H, 2 * H);
}

// Round 10
// 681.210 us; speedup vs baseline: 1.9186x; 1.0860x over previous
//
#include <hip/hip_runtime.h>
#include <math.h>

// ---------------- problem constants ----------------
#define H 256
#define S_STEPS 4
#define B_RXN 512
#define N_MOLS 2048          // B*S
#define ATOMS_PER_MOL 32
#define N_ATOMS 65536        // N_MOLS*32
#define N_BONDS 131072
#define NBP1 131073          // N_BONDS+1
#define MAX_NB 6
#define ATOM_FDIM 133
#define BOND_FDIM 147
#define DEPTH 3
#define N_ITERS 3

typedef unsigned short bf16u;
typedef __attribute__((ext_vector_type(8))) short short8v;  // 8 bf16 = 4 VGPR
typedef __attribute__((ext_vector_type(4))) float f32x4;

__device__ __forceinline__ float b2f(bf16u u) {
    union { unsigned int i; float f; } c; c.i = ((unsigned int)u) << 16; return c.f;
}
__device__ __forceinline__ bf16u f2b(float f) {
    union { float f; unsigned int i; } c; c.f = f;
    unsigned int i = c.i;
    return (bf16u)((i + 0x7FFFu + ((i >> 16) & 1u)) >> 16);   // RNE
}
__device__ __forceinline__ unsigned int relu2bf(unsigned int w) {
    unsigned int lo = w & 0xFFFFu, hi = w >> 16;
    if (lo & 0x8000u) lo = 0u;
    if (hi & 0x8000u) hi = 0u;
    return lo | (hi << 16);
}

// ============ dense MFMA GEMM (bond/atom): BM=128, 512 thr / 8 waves ============
// C[M,256] = epi(A[M,KP] @ WT^T). A contiguous bf16; single-buffer LDS (proven).
// MODE 0 (WI):   A = FB16 [M,160];              epi: INP = bf16(acc)
// MODE 1 (MW):   A = msg-source [M,256] (opt. relu in staging); epi: MW = bf16(acc)
// MODE 2 (ATOM): A = [FA16 160 | AMSG 256] (KP=416); epi: bf16 relu(acc+bias)
template<int MODE, bool RELUA>
__global__ __launch_bounds__(512) void dense_gemm_k(
    const bf16u* __restrict__ A1,
    const bf16u* __restrict__ A2,     // MODE2 only
    const bf16u* __restrict__ WT,     // [256][KP] bf16
    const float* __restrict__ bias,   // MODE2 only
    bf16u* __restrict__ outb,
    int M)
{
    constexpr int KP = (MODE == 0) ? 160 : ((MODE == 1) ? 256 : 416);
    __shared__ bf16u As[128][40];
    __shared__ bf16u Bs[256][40];

    const int tid = threadIdx.x;
    const int lane = tid & 63, w = tid >> 6;      // 8 waves
    const int wr = w >> 2, wc = w & 3;            // 2 x 4 wave grid
    const int m0 = blockIdx.x * 128;
    const int ar = tid >> 2, q8 = (tid & 3) * 8;  // A stage: row, k-chunk
    const int br = tid >> 1, bh = (tid & 1) * 16; // B stage: row, k-half
    const int arow = m0 + ar;
    const bool rok = arow < M;
    const int lr = lane & 15, lk = (lane >> 4) * 8;
    const uint4 z4 = {0u, 0u, 0u, 0u};

    f32x4 acc[4][4];
    const f32x4 zf = {0.f, 0.f, 0.f, 0.f};
    #pragma unroll
    for (int i = 0; i < 4; ++i)
        #pragma unroll
        for (int j = 0; j < 4; ++j) acc[i][j] = zf;

    for (int k0 = 0; k0 < KP; k0 += 32) {
        // ---- stage A: one uint4 per thread (contiguous) ----
        const int kc = k0 + q8;
        uint4 va;
        if (MODE == 2) {
            va = (kc < 160) ? *(const uint4*)(A1 + (size_t)arow * 160 + kc)
                            : *(const uint4*)(A2 + (size_t)arow * 256 + (kc - 160));
        } else {
            constexpr int LDA = (MODE == 0) ? 160 : 256;
            va = rok ? *(const uint4*)(A1 + (size_t)arow * LDA + kc) : z4;
        }
        if (RELUA) {
            va.x = relu2bf(va.x); va.y = relu2bf(va.y);
            va.z = relu2bf(va.z); va.w = relu2bf(va.w);
        }
        *(uint4*)&As[ar][q8] = va;
        // ---- stage B: 2 uint4 per thread ----
        {
            const bf16u* bp = WT + (size_t)br * KP + k0 + bh;
            uint4 b0 = *(const uint4*)(bp);
            uint4 b1 = *(const uint4*)(bp + 8);
            *(uint4*)&Bs[br][bh] = b0;
            *(uint4*)&Bs[br][bh + 8] = b1;
        }
        __syncthreads();

        short8v a[4], b[4];
        #pragma unroll
        for (int mf = 0; mf < 4; ++mf)
            a[mf] = *(const short8v*)&As[wr * 64 + mf * 16 + lr][lk];
        #pragma unroll
        for (int nf = 0; nf < 4; ++nf)
            b[nf] = *(const short8v*)&Bs[wc * 64 + nf * 16 + lr][lk];
        #pragma unroll
        for (int mf = 0; mf < 4; ++mf)
            #pragma unroll
            for (int nf = 0; nf < 4; ++nf)
                acc[mf][nf] = __builtin_amdgcn_mfma_f32_16x16x32_bf16(
                    a[mf], b[nf], acc[mf][nf], 0, 0, 0);
        __syncthreads();
    }

    const int rbase = (lane >> 4) * 4;
    #pragma unroll
    for (int mf = 0; mf < 4; ++mf) {
        #pragma unroll
        for (int nf = 0; nf < 4; ++nf) {
            const int col = wc * 64 + nf * 16 + lr;
            #pragma unroll
            for (int r = 0; r < 4; ++r) {
                const int row = m0 + wr * 64 + mf * 16 + rbase + r;
                if (row >= M) continue;
                float v = acc[mf][nf][r];
                const size_t off = (size_t)row * H + col;
                if (MODE == 2) {
                    v += bias[col];
                    outb[off] = f2b(fmaxf(v, 0.f));
                } else {
                    outb[off] = f2b(v);
                }
            }
        }
    }
}

// ---- combine: msg[b] = relu(inp[b] + AP[b2a[b]] - MW[b2revb[b]]), row 0 = 0 ----
__global__ __launch_bounds__(256) void combine_k(
    const bf16u* __restrict__ inp, const bf16u* __restrict__ AP,
    const bf16u* __restrict__ MW,
    const int* __restrict__ b2a, const int* __restrict__ b2revb,
    bf16u* __restrict__ msg)
{
    int idx = blockIdx.x * 256 + threadIdx.x;
    if (idx >= NBP1 * 32) return;
    int b = idx >> 5, c = (idx & 31) * 8;
    bf16u* op = msg + (size_t)b * H + c;
    if (b == 0) {
        *(uint4*)op = make_uint4(0u, 0u, 0u, 0u);
        return;
    }
    int a = b2a[b], rb = b2revb[b];
    uint4 ui = *(const uint4*)(inp + (size_t)b * H + c);
    uint4 up = *(const uint4*)(AP + (size_t)a * H + c);
    uint4 um = *(const uint4*)(MW + (size_t)rb * H + c);
    uint4 o;
    unsigned int* pi = &ui.x; unsigned int* pp = &up.x;
    unsigned int* pm = &um.x; unsigned int* po = &o.x;
    #pragma unroll
    for (int t = 0; t < 4; ++t) {
        float lo = b2f((bf16u)(pi[t] & 0xFFFFu)) + b2f((bf16u)(pp[t] & 0xFFFFu))
                 - b2f((bf16u)(pm[t] & 0xFFFFu));
        float hi = b2f((bf16u)(pi[t] >> 16)) + b2f((bf16u)(pp[t] >> 16))
                 - b2f((bf16u)(pm[t] >> 16));
        lo = fmaxf(lo, 0.f); hi = fmaxf(hi, 0.f);
        po[t] = (unsigned int)f2b(lo) | ((unsigned int)f2b(hi) << 16);
    }
    *(uint4*)op = o;
}

// ============ mid-phase MFMA linear, BM=64 x BN=64 (round-9 proven) ============
template<bool BIAS>
__global__ __launch_bounds__(256) void lin64_k(
    const float* __restrict__ A1, int lda1, int KA1,
    const float* __restrict__ A2, int lda2,
    const bf16u* __restrict__ WT, int ldw,
    const float* __restrict__ bias,
    float* __restrict__ C, int ldc, int K)
{
    __shared__ bf16u As[64][40];
    __shared__ bf16u Bs[64][40];
    const int tid = threadIdx.x;
    const int lane = tid & 63, w = tid >> 6;
    const int m0 = blockIdx.x * 64;
    const int col0 = blockIdx.y * 64;
    const int ar = tid >> 2, kq8 = (tid & 3) * 8;
    const int lr = lane & 15, lk = (lane >> 4) * 8;

    f32x4 acc[4];
    const f32x4 zf = {0.f, 0.f, 0.f, 0.f};
    #pragma unroll
    for (int j = 0; j < 4; ++j) acc[j] = zf;

    for (int k0 = 0; k0 < K; k0 += 32) {
        const float* src = (k0 < KA1)
            ? (A1 + (size_t)(m0 + ar) * lda1 + k0 + kq8)
            : (A2 + (size_t)(m0 + ar) * lda2 + (k0 - KA1) + kq8);
        float4 f0 = *(const float4*)src;
        float4 f1 = *(const float4*)(src + 4);
        ushort4 s0, s1;
        s0.x = f2b(f0.x); s0.y = f2b(f0.y); s0.z = f2b(f0.z); s0.w = f2b(f0.w);
        s1.x = f2b(f1.x); s1.y = f2b(f1.y); s1.z = f2b(f1.z); s1.w = f2b(f1.w);
        *(ushort4*)&As[ar][kq8] = s0;
        *(ushort4*)&As[ar][kq8 + 4] = s1;
        *(uint4*)&Bs[ar][kq8] = *(const uint4*)(WT + (size_t)(col0 + ar) * ldw + k0 + kq8);
        __syncthreads();

        short8v a = *(const short8v*)&As[w * 16 + lr][lk];
        short8v b[4];
        #pragma unroll
        for (int nf = 0; nf < 4; ++nf)
            b[nf] = *(const short8v*)&Bs[nf * 16 + lr][lk];
        #pragma unroll
        for (int nf = 0; nf < 4; ++nf)
            acc[nf] = __builtin_amdgcn_mfma_f32_16x16x32_bf16(a, b[nf], acc[nf], 0, 0, 0);
        __syncthreads();
    }

    const int rbase = (lane >> 4) * 4;
    #pragma unroll
    for (int nf = 0; nf < 4; ++nf) {
        const int col = col0 + nf * 16 + lr;
        #pragma unroll
        for (int r = 0; r < 4; ++r) {
            const int row = m0 + w * 16 + rbase + r;
            float v = acc[nf][r];
            if (BIAS) v += bias[col];
            C[(size_t)row * ldc + col] = v;
        }
    }
}

// ---------------- prep kernels ----------------
__global__ __launch_bounds__(256) void prep_wt_k(const float* __restrict__ W,
                                                 bf16u* __restrict__ WT, int K, int KP)
{
    int idx = blockIdx.x * 256 + threadIdx.x;
    if (idx >= 256 * KP) return;
    int n = idx / KP, k = idx - n * KP;
    WT[idx] = (k < K) ? f2b(W[(size_t)k * H + n]) : (bf16u)0;
}

__global__ __launch_bounds__(256) void prep_wto_k(const float* __restrict__ Wo,
                                                  bf16u* __restrict__ WT)
{
    int idx = blockIdx.x * 256 + threadIdx.x;
    if (idx >= 256 * 416) return;
    int n = idx / 416, k = idx - n * 416;
    float v = 0.f;
    if (k < ATOM_FDIM) v = Wo[(size_t)k * H + n];
    else if (k >= 160) v = Wo[(size_t)(ATOM_FDIM + k - 160) * H + n];
    WT[idx] = f2b(v);
}

__global__ __launch_bounds__(256) void prep_wt_t_k(const float* __restrict__ W,
                                                   bf16u* __restrict__ WT, int K)
{
    int idx = blockIdx.x * 256 + threadIdx.x;
    if (idx >= 256 * K) return;
    int n = idx / K, k = idx - n * K;
    WT[idx] = f2b(W[(size_t)k * 256 + n]);
}

__global__ __launch_bounds__(256) void prep_wt_gates_k(const float* __restrict__ Wih,
                                                       const float* __restrict__ Whh,
                                                       bf16u* __restrict__ WT)
{
    int idx = blockIdx.x * 256 + threadIdx.x;
    if (idx >= 1024 * 768) return;
    int n = idx / 768, k = idx - n * 768;
    WT[idx] = f2b(k < 512 ? Wih[(size_t)n * 512 + k] : Whh[(size_t)n * 256 + (k - 512)]);
}

// fused PQS: WT [768][256]; rows 0-255: W_nn0 top; 256-511: W_nn0 bottom; 512-767: W_nn0s
__global__ __launch_bounds__(256) void prep_wt_pqs_k(const float* __restrict__ Wnn0,
                                                     const float* __restrict__ Wnn0s,
                                                     bf16u* __restrict__ WT,
                                                     float* __restrict__ bias_pqs,
                                                     const float* __restrict__ b_nn0s)
{
    int idx = blockIdx.x * 256 + threadIdx.x;
    if (idx < 768) bias_pqs[idx] = (idx < 512) ? 0.f : b_nn0s[idx - 512];
    if (idx >= 768 * 256) return;
    int n = idx / 256, k = idx - n * 256;
    float v;
    if (n < 256)      v = Wnn0[(size_t)k * 256 + n];
    else if (n < 512) v = Wnn0[(size_t)(256 + k) * 256 + (n - 256)];
    else              v = Wnn0s[(size_t)k * 256 + (n - 512)];
    WT[idx] = f2b(v);
}

__global__ __launch_bounds__(256) void prep_feat16_k(const float* __restrict__ F,
                                                     bf16u* __restrict__ O,
                                                     int rows, int K)
{
    int idx = blockIdx.x * 256 + threadIdx.x;
    if (idx >= rows * 160) return;
    int r = idx / 160, c = idx - r * 160;
    O[idx] = (c < K) ? f2b(F[(size_t)r * K + c]) : (bf16u)0;
}

// ---------------- small kernels ----------------
__global__ __launch_bounds__(256) void gather6_bf16_k(const bf16u* __restrict__ msg,
                                                      const int* __restrict__ a2b,
                                                      bf16u* __restrict__ outb)
{
    int idx = blockIdx.x * 256 + threadIdx.x;
    if (idx >= N_ATOMS * (H / 8)) return;
    int na = idx >> 5, c = idx & 31;
    const int* nb = a2b + (size_t)na * MAX_NB;
    float s[8] = {0.f, 0.f, 0.f, 0.f, 0.f, 0.f, 0.f, 0.f};
    #pragma unroll
    for (int j = 0; j < MAX_NB; ++j) {
        uint4 u = *(const uint4*)(msg + (size_t)nb[j] * H + c * 8);
        s[0] += b2f((bf16u)(u.x & 0xFFFFu)); s[1] += b2f((bf16u)(u.x >> 16));
        s[2] += b2f((bf16u)(u.y & 0xFFFFu)); s[3] += b2f((bf16u)(u.y >> 16));
        s[4] += b2f((bf16u)(u.z & 0xFFFFu)); s[5] += b2f((bf16u)(u.z >> 16));
        s[6] += b2f((bf16u)(u.w & 0xFFFFu)); s[7] += b2f((bf16u)(u.w >> 16));
    }
    uint4 o;
    o.x = (unsigned int)f2b(s[0]) | ((unsigned int)f2b(s[1]) << 16);
    o.y = (unsigned int)f2b(s[2]) | ((unsigned int)f2b(s[3]) << 16);
    o.z = (unsigned int)f2b(s[4]) | ((unsigned int)f2b(s[5]) << 16);
    o.w = (unsigned int)f2b(s[6]) | ((unsigned int)f2b(s[7]) << 16);
    *(uint4*)(outb + (size_t)na * H + c * 8) = o;
}

__global__ __launch_bounds__(256) void zero_f32_k(float* __restrict__ p, int n)
{
    int idx = blockIdx.x * 256 + threadIdx.x;
    if (idx < n) p[idx] = 0.f;
}

__device__ __forceinline__ float sigm(float x) { return 1.f / (1.f + expf(-x)); }

__global__ __launch_bounds__(256) void lstm_pw_k(const float* __restrict__ gates,
                                                 float* __restrict__ h,
                                                 float* __restrict__ c, int M)
{
    int idx = blockIdx.x * 256 + threadIdx.x;
    if (idx >= M * H) return;
    int m = idx >> 8, d = idx & 255;
    const float* g = gates + (size_t)m * (4 * H);
    float ig = sigm(g[d]);
    float fg = sigm(g[H + d]);
    float gg = tanhf(g[2 * H + d]);
    float og = sigm(g[3 * H + d]);
    float cn = fg * c[idx] + ig * gg;
    c[idx] = cn;
    h[idx] = og * tanhf(cn);
}

// feat bf16 (BF16F) or f32; h/q_star f32
template<bool BF16F>
__global__ __launch_bounds__(256) void s2s_attn_k(const void* __restrict__ featv,
                                                  const float* __restrict__ h,
                                                  float* __restrict__ q_star, int Nn)
{
    int m = blockIdx.x;
    int t = threadIdx.x;
    int lane = t & 63, wave = t >> 6;
    __shared__ float sc[32];
    const bf16u* fb = (const bf16u*)featv;
    const float* ff = (const float*)featv;
    const size_t fbase = (size_t)m * Nn * H;
    const float* hm = h + (size_t)m * H;
    for (int n = wave; n < Nn; n += 4) {
        float p = 0.f;
        if (BF16F) {
            ushort4 u = *(const ushort4*)(fb + fbase + (size_t)n * H + lane * 4);
            const float4 h4 = *(const float4*)(hm + lane * 4);
            p = b2f(u.x) * h4.x + b2f(u.y) * h4.y + b2f(u.z) * h4.z + b2f(u.w) * h4.w;
        } else {
            const float* fr = ff + fbase + (size_t)n * H;
            #pragma unroll
            for (int u = 0; u < 4; ++u) p += fr[lane * 4 + u] * hm[lane * 4 + u];
        }
        #pragma unroll
        for (int o = 32; o >= 1; o >>= 1) p += __shfl_xor(p, o);
        if (lane == 0) sc[n] = p;
    }
    __syncthreads();
    float mx = -1e30f;
    for (int n = 0; n < Nn; ++n) mx = fmaxf(mx, sc[n]);
    float ssum = 0.f, r = 0.f;
    for (int n = 0; n < Nn; ++n) {
        float a = expf(sc[n] - mx);
        ssum += a;
        float fv = BF16F ? b2f(fb[fbase + (size_t)n * H + t]) : ff[fbase + (size_t)n * H + t];
        r += a * fv;
    }
    r /= ssum;
    q_star[(size_t)m * (2 * H) + t] = hm[t];
    q_star[(size_t)m * (2 * H) + H + t] = r;
}

// X[b,s1,s2,:] from packed PQS [2048][768]: P = +0, Q = +256, SO = +512
__global__ __launch_bounds__(256) void build_x_k(const float* __restrict__ PQS,
                                                 const float* __restrict__ b0,
                                                 float* __restrict__ X)
{
    int idx = blockIdx.x * 256 + threadIdx.x;
    if (idx >= B_RXN * S_STEPS * S_STEPS * H) return;
    int d  = idx & 255;
    int s2 = (idx >> 8) & 3;
    int s1 = (idx >> 10) & 3;
    int b  = idx >> 12;
    float v;
    if (s1 == s2) v = PQS[((size_t)(b * S_STEPS + s1)) * 768 + 512 + d];
    else v = PQS[((size_t)(b * S_STEPS + s1)) * 768 + d]
           + PQS[((size_t)(b * S_STEPS + s2)) * 768 + 256 + d] + b0[d];
    X[idx] = v;
}

// ---------------- launch ----------------
extern "C" void kernel_launch(void* const* d_in, const int* in_sizes, int n_in,
                              void* d_out, int out_size, void* d_ws, size_t ws_size,
                              hipStream_t stream)
{
    const float* f_atoms   = (const float*)d_in[0];
    const float* f_bonds   = (const float*)d_in[1];
    const int*   a2b       = (const int*)d_in[2];
    const int*   b2a       = (const int*)d_in[3];
    const int*   b2revb    = (const int*)d_in[4];
    const float* W_i       = (const float*)d_in[5];
    const float* W_h       = (const float*)d_in[6];
    const float* W_o       = (const float*)d_in[7];
    const float* b_o       = (const float*)d_in[8];
    const float* W_nn0     = (const float*)d_in[9];
    const float* b_nn0     = (const float*)d_in[10];
    const float* W_nn0s    = (const float*)d_in[11];
    const float* b_nn0s    = (const float*)d_in[12];
    const float* W_nn1     = (const float*)d_in[13];
    const float* b_nn1     = (const float*)d_in[14];
    const float* lstm_n_Wih = (const float*)d_in[15];
    const float* lstm_n_Whh = (const float*)d_in[16];
    const float* lstm_n_b   = (const float*)d_in[17];
    const float* node_cond_W = (const float*)d_in[18];
    const float* node_cond_b = (const float*)d_in[19];
    const float* lstm_g_Wih = (const float*)d_in[20];
    const float* lstm_g_Whh = (const float*)d_in[21];
    const float* lstm_g_b   = (const float*)d_in[22];
    const float* graph_cond_W = (const float*)d_in[23];
    const float* graph_cond_b = (const float*)d_in[24];
    float* out = (float*)d_out;

    // ---- workspace layout (~235 MB) ----
    const size_t SZB = (size_t)NBP1 * H * sizeof(bf16u);    // 67,109,376 B
    char* base = (char*)d_ws;
    bf16u* INP  = (bf16u*)(base);                            // [NBP1,H]
    bf16u* MSG  = (bf16u*)(base + SZB);                      // [NBP1,H]
    bf16u* MW   = (bf16u*)(base + 2 * SZB);                  // [NBP1,H]
    bf16u* AMSG = (bf16u*)(base + 3 * SZB);                  // [N_ATOMS,H]
    bf16u* WT_I = (bf16u*)(base + 3 * SZB + 33554432);       // [256][160]
    bf16u* WT_H = (bf16u*)(base + 3 * SZB + 33636352);       // [256][256]
    bf16u* WT_O = (bf16u*)(base + 3 * SZB + 33767424);       // [256][416]
    // aliases:
    bf16u* FB16 = MW;                                        // before 1st MW
    bf16u* FA16 = MW;                                        // after last combine
    bf16u* ATOMH16 = (bf16u*)(base);                         // bf16 feat, alias INP (dead)
    float* SMALL = (float*)(base + SZB);                     // f32 scratch, alias MSG (dead)
    float* GATES  = SMALL;                                   // [2048,1024]
    float* HN     = SMALL + 2097152;                         // [2048,256]
    float* CN     = SMALL + 2621440;                         // [2048,256]
    float* QSTARN = SMALL + 3145728;                         // [2048,512]
    float* MOL    = SMALL + 4194304;                         // [2048,256]
    float* PQS    = SMALL + 4718592;                         // [2048,768]
    float* XBUF   = SMALL + 6291456;                         // [8192,256]
    float* STEPS  = SMALL + 8388608;                         // [2048,256]
    float* HG     = SMALL + 8912896;                         // [512,256]
    float* CG     = SMALL + 9043968;                         // [512,256]
    float* QSTARG = SMALL + 9175040;                         // [512,512]
    float* GATESG = SMALL + 9437184;                         // [512,1024]
    char* sm2 = base + 2 * SZB + 25165824;                   // MW dead zone
    bf16u* WTG_N   = (bf16u*)(sm2);                  // [1024][768]
    bf16u* WTG_G   = (bf16u*)(sm2 + 1572864);        // [1024][768]
    bf16u* WT_NC   = (bf16u*)(sm2 + 3145728);        // [256][512]
    bf16u* WT_PQS  = (bf16u*)(sm2 + 3407872);        // [768][256]
    bf16u* WT_N1   = (bf16u*)(sm2 + 3801088);        // [256][1024]
    bf16u* WT_GC   = (bf16u*)(sm2 + 4325376);        // [256][512]
    float* BIAS_PQS = (float*)(sm2 + 4587520);       // [768]

    dim3 blk(256), blk5(512);
    const int MB_BOND = (NBP1 + 127) / 128;   // 1025
    const int MB_ATOM = N_ATOMS / 128;        // 512
    const int G_GATH = (N_ATOMS * (H / 8) + 255) / 256;
    const int G_COMB = (NBP1 * 32 + 255) / 256;

    // 0. weight + input prep
    prep_wt_k<<<(256 * 160 + 255) / 256, blk, 0, stream>>>(W_i, WT_I, BOND_FDIM, 160);
    prep_wt_k<<<(256 * 256 + 255) / 256, blk, 0, stream>>>(W_h, WT_H, H, 256);
    prep_wto_k<<<(256 * 416 + 255) / 256, blk, 0, stream>>>(W_o, WT_O);
    prep_feat16_k<<<(int)(((size_t)NBP1 * 160 + 255) / 256), blk, 0, stream>>>(
        f_bonds, FB16, NBP1, BOND_FDIM);

    // 1. INP = FB16 @ W_i  (no separate relu buffer; relu applied in MW staging)
    dense_gemm_k<0, false><<<MB_BOND, blk5, 0, stream>>>(
        FB16, nullptr, WT_I, nullptr, INP, NBP1);

    // 2. depth loop
    // iter 0: MW = relu(INP) @ W_h (relu in staging); combine -> MSG
    dense_gemm_k<1, true><<<MB_BOND, blk5, 0, stream>>>(
        INP, nullptr, WT_H, nullptr, MW, NBP1);
    gather6_bf16_k<<<G_GATH, blk, 0, stream>>>(MW, a2b, AMSG);
    combine_k<<<G_COMB, blk, 0, stream>>>(INP, AMSG, MW, b2a, b2revb, MSG);
    // iter 1: MW = MSG @ W_h; combine -> MSG
    dense_gemm_k<1, false><<<MB_BOND, blk5, 0, stream>>>(
        MSG, nullptr, WT_H, nullptr, MW, NBP1);
    gather6_bf16_k<<<G_GATH, blk, 0, stream>>>(MW, a2b, AMSG);
    combine_k<<<G_COMB, blk, 0, stream>>>(INP, AMSG, MW, b2a, b2revb, MSG);

    // 3. nei = gather6(final MSG)
    gather6_bf16_k<<<G_GATH, blk, 0, stream>>>(MSG, a2b, AMSG);

    // 3b. packed f_atoms + mid-phase weight prep (MW region dead)
    prep_feat16_k<<<(N_ATOMS * 160 + 255) / 256, blk, 0, stream>>>(
        f_atoms, FA16, N_ATOMS, ATOM_FDIM);
    prep_wt_gates_k<<<(1024 * 768 + 255) / 256, blk, 0, stream>>>(lstm_n_Wih, lstm_n_Whh, WTG_N);
    prep_wt_gates_k<<<(1024 * 768 + 255) / 256, blk, 0, stream>>>(lstm_g_Wih, lstm_g_Whh, WTG_G);
    prep_wt_t_k<<<(256 * 512 + 255) / 256, blk, 0, stream>>>(node_cond_W, WT_NC, 512);
    prep_wt_pqs_k<<<(768 * 256 + 255) / 256, blk, 0, stream>>>(W_nn0, W_nn0s, WT_PQS, BIAS_PQS, b_nn0s);
    prep_wt_t_k<<<(256 * 1024 + 255) / 256, blk, 0, stream>>>(W_nn1, WT_N1, 1024);
    prep_wt_t_k<<<(256 * 512 + 255) / 256, blk, 0, stream>>>(graph_cond_W, WT_GC, 512);

    // 4. atom_h = relu([f_atoms, nei] @ W_o + b_o) -> ATOMH16 bf16 (aliases dead INP)
    dense_gemm_k<2, false><<<MB_ATOM, blk5, 0, stream>>>(
        FA16, AMSG, WT_O, b_o, ATOMH16, N_ATOMS);

    // 5. node Set2Set over [2048, 32, 256]
    zero_f32_k<<<(2097152 + 255) / 256, blk, 0, stream>>>(HN, 2097152);  // HN,CN,QSTARN
    for (int it = 0; it < N_ITERS; ++it) {
        lin64_k<true><<<dim3(N_MOLS / 64, 16), blk, 0, stream>>>(
            QSTARN, 2 * H, 2 * H, HN, H, WTG_N, 3 * H, lstm_n_b, GATES, 4 * H, 3 * H);
        lstm_pw_k<<<(N_MOLS * H) / 256, blk, 0, stream>>>(GATES, HN, CN, N_MOLS);
        s2s_attn_k<true><<<N_MOLS, blk, 0, stream>>>(ATOMH16, HN, QSTARN, ATOMS_PER_MOL);
    }
    lin64_k<true><<<dim3(N_MOLS / 64, 4), blk, 0, stream>>>(
        QSTARN, 2 * H, 2 * H, QSTARN, 2 * H, WT_NC, 2 * H, node_cond_b, MOL, H, 2 * H);

    // 6. NN attention over steps (fused P|Q|SO GEMM)
    lin64_k<true><<<dim3(N_MOLS / 64, 12), blk, 0, stream>>>(
        MOL, H, H, MOL, H, WT_PQS, H, BIAS_PQS, PQS, 3 * H, H);
    build_x_k<<<(B_RXN * 16 * H) / 256, blk, 0, stream>>>(PQS, b_nn0, XBUF);
    lin64_k<true><<<dim3(N_MOLS / 64, 4), blk, 0, stream>>>(
        XBUF, S_STEPS * H, S_STEPS * H, XBUF, S_STEPS * H, WT_N1, S_STEPS * H, b_nn1,
        STEPS, H, S_STEPS * H);

    // 7. graph Set2Set over [512, 4, 256]
    zero_f32_k<<<(524288 + 255) / 256, blk, 0, stream>>>(HG, 524288);    // HG,CG,QSTARG
    for (int it = 0; it < N_ITERS; ++it) {
        lin64_k<true><<<dim3(B_RXN / 64, 16), blk, 0, stream>>>(
            QSTARG, 2 * H, 2 * H, HG, H, WTG_G, 3 * H, lstm_g_b, GATESG, 4 * H, 3 * H);
        lstm_pw_k<<<(B_RXN * H) / 256, blk, 0, stream>>>(GATESG, HG, CG, B_RXN);
        s2s_attn_k<false><<<B_RXN, blk, 0, stream>>>(STEPS, HG, QSTARG, S_STEPS);
    }

    // 8. out
    lin64_k<true><<<dim3(B_RXN / 64, 4), blk, 0, stream>>>(
        QSTARG, 2 * H, 2 * H, QSTARG, 2 * H, WT_GC, 2 * H, graph_cond_b, out, H, 2 * H);
}

// Round 11
// 676.852 us; speedup vs baseline: 1.9310x; 1.0064x over previous
//
#include <hip/hip_runtime.h>
#include <math.h>

// ---------------- problem constants ----------------
#define H 256
#define S_STEPS 4
#define B_RXN 512
#define N_MOLS 2048          // B*S
#define ATOMS_PER_MOL 32
#define N_ATOMS 65536        // N_MOLS*32
#define N_BONDS 131072
#define NBP1 131073          // N_BONDS+1
#define MAX_NB 6
#define ATOM_FDIM 133
#define BOND_FDIM 147
#define DEPTH 3
#define N_ITERS 3

typedef unsigned short bf16u;
typedef __attribute__((ext_vector_type(8))) short short8v;  // 8 bf16 = 4 VGPR
typedef __attribute__((ext_vector_type(4))) float f32x4;

__device__ __forceinline__ float b2f(bf16u u) {
    union { unsigned int i; float f; } c; c.i = ((unsigned int)u) << 16; return c.f;
}
__device__ __forceinline__ bf16u f2b(float f) {
    union { float f; unsigned int i; } c; c.f = f;
    unsigned int i = c.i;
    return (bf16u)((i + 0x7FFFu + ((i >> 16) & 1u)) >> 16);   // RNE
}
__device__ __forceinline__ unsigned int relu2bf(unsigned int w) {
    unsigned int lo = w & 0xFFFFu, hi = w >> 16;
    if (lo & 0x8000u) lo = 0u;
    if (hi & 0x8000u) hi = 0u;
    return lo | (hi << 16);
}

// ============ dense MFMA GEMM (bond/atom): BM=128, 512 thr, load-early overlap ============
// Per step: issue s+1 loads (loop-local regs) -> MFMA step s -> barrier -> ds_write -> barrier.
// MODE 0 (WI):   A = FB16 [M,160];              epi: INP = bf16(acc)
// MODE 1 (MW):   A = msg-source [M,256] (opt. relu in staging); epi: MW = bf16(acc)
// MODE 2 (ATOM): A = [FA16 160 | AMSG 256] (KP=416); epi: bf16 relu(acc+bias)
template<int MODE, bool RELUA>
__global__ __launch_bounds__(512) void dense_gemm_k(
    const bf16u* __restrict__ A1,
    const bf16u* __restrict__ A2,     // MODE2 only
    const bf16u* __restrict__ WT,     // [256][KP] bf16
    const float* __restrict__ bias,   // MODE2 only
    bf16u* __restrict__ outb,
    int M)
{
    constexpr int KP = (MODE == 0) ? 160 : ((MODE == 1) ? 256 : 416);
    constexpr int NS = KP / 32;
    __shared__ bf16u As[128][40];
    __shared__ bf16u Bs[256][40];

    const int tid = threadIdx.x;
    const int lane = tid & 63, w = tid >> 6;      // 8 waves
    const int wr = w >> 2, wc = w & 3;            // 2 x 4 wave grid
    const int m0 = blockIdx.x * 128;
    const int ar = tid >> 2, q8 = (tid & 3) * 8;  // A stage: row, k-chunk
    const int br = tid >> 1, bh = (tid & 1) * 16; // B stage: row, k-half
    const int arow = m0 + ar;
    const bool rok = arow < M;
    const int lr = lane & 15, lk = (lane >> 4) * 8;
    const uint4 z4 = {0u, 0u, 0u, 0u};

    auto loadA = [&](int s) -> uint4 {
        const int kc = s * 32 + q8;
        if (MODE == 2) {
            return (kc < 160) ? *(const uint4*)(A1 + (size_t)arow * 160 + kc)
                              : *(const uint4*)(A2 + (size_t)arow * 256 + (kc - 160));
        } else {
            constexpr int LDA = (MODE == 0) ? 160 : 256;
            return rok ? *(const uint4*)(A1 + (size_t)arow * LDA + kc) : z4;
        }
    };
    auto loadB0 = [&](int s) { return *(const uint4*)(WT + (size_t)br * KP + s * 32 + bh); };
    auto loadB1 = [&](int s) { return *(const uint4*)(WT + (size_t)br * KP + s * 32 + bh + 8); };
    auto writeAB = [&](uint4 va, uint4 vb0, uint4 vb1) {
        if (RELUA) {
            va.x = relu2bf(va.x); va.y = relu2bf(va.y);
            va.z = relu2bf(va.z); va.w = relu2bf(va.w);
        }
        *(uint4*)&As[ar][q8] = va;
        *(uint4*)&Bs[br][bh] = vb0;
        *(uint4*)&Bs[br][bh + 8] = vb1;
    };

    f32x4 acc[4][4];
    const f32x4 zf = {0.f, 0.f, 0.f, 0.f};
    #pragma unroll
    for (int i = 0; i < 4; ++i)
        #pragma unroll
        for (int j = 0; j < 4; ++j) acc[i][j] = zf;

    // prologue: stage tile 0
    writeAB(loadA(0), loadB0(0), loadB1(0));
    __syncthreads();

    for (int s = 0; s < NS; ++s) {
        const bool pf = (s + 1 < NS);
        uint4 va = z4, vb0 = z4, vb1 = z4;
        if (pf) { va = loadA(s + 1); vb0 = loadB0(s + 1); vb1 = loadB1(s + 1); }

        short8v a[4], b[4];
        #pragma unroll
        for (int mf = 0; mf < 4; ++mf)
            a[mf] = *(const short8v*)&As[wr * 64 + mf * 16 + lr][lk];
        #pragma unroll
        for (int nf = 0; nf < 4; ++nf)
            b[nf] = *(const short8v*)&Bs[wc * 64 + nf * 16 + lr][lk];
        #pragma unroll
        for (int mf = 0; mf < 4; ++mf)
            #pragma unroll
            for (int nf = 0; nf < 4; ++nf)
                acc[mf][nf] = __builtin_amdgcn_mfma_f32_16x16x32_bf16(
                    a[mf], b[nf], acc[mf][nf], 0, 0, 0);
        __syncthreads();                 // all reads of the buffer done
        if (pf) {
            writeAB(va, vb0, vb1);       // vmcnt drain here, after compute overlap
            __syncthreads();
        }
    }

    const int rbase = (lane >> 4) * 4;
    #pragma unroll
    for (int mf = 0; mf < 4; ++mf) {
        #pragma unroll
        for (int nf = 0; nf < 4; ++nf) {
            const int col = wc * 64 + nf * 16 + lr;
            #pragma unroll
            for (int r = 0; r < 4; ++r) {
                const int row = m0 + wr * 64 + mf * 16 + rbase + r;
                if (row >= M) continue;
                float v = acc[mf][nf][r];
                const size_t off = (size_t)row * H + col;
                if (MODE == 2) {
                    v += bias[col];
                    outb[off] = f2b(fmaxf(v, 0.f));
                } else {
                    outb[off] = f2b(v);
                }
            }
        }
    }
}

// ---- combine: msg[b] = relu(inp[b] + AP[b2a[b]] - MW[b2revb[b]]), row 0 = 0 ----
__global__ __launch_bounds__(256) void combine_k(
    const bf16u* __restrict__ inp, const bf16u* __restrict__ AP,
    const bf16u* __restrict__ MW,
    const int* __restrict__ b2a, const int* __restrict__ b2revb,
    bf16u* __restrict__ msg)
{
    int idx = blockIdx.x * 256 + threadIdx.x;
    if (idx >= NBP1 * 32) return;
    int b = idx >> 5, c = (idx & 31) * 8;
    bf16u* op = msg + (size_t)b * H + c;
    if (b == 0) {
        *(uint4*)op = make_uint4(0u, 0u, 0u, 0u);
        return;
    }
    int a = b2a[b], rb = b2revb[b];
    uint4 ui = *(const uint4*)(inp + (size_t)b * H + c);
    uint4 up = *(const uint4*)(AP + (size_t)a * H + c);
    uint4 um = *(const uint4*)(MW + (size_t)rb * H + c);
    uint4 o;
    unsigned int* pi = &ui.x; unsigned int* pp = &up.x;
    unsigned int* pm = &um.x; unsigned int* po = &o.x;
    #pragma unroll
    for (int t = 0; t < 4; ++t) {
        float lo = b2f((bf16u)(pi[t] & 0xFFFFu)) + b2f((bf16u)(pp[t] & 0xFFFFu))
                 - b2f((bf16u)(pm[t] & 0xFFFFu));
        float hi = b2f((bf16u)(pi[t] >> 16)) + b2f((bf16u)(pp[t] >> 16))
                 - b2f((bf16u)(pm[t] >> 16));
        lo = fmaxf(lo, 0.f); hi = fmaxf(hi, 0.f);
        po[t] = (unsigned int)f2b(lo) | ((unsigned int)f2b(hi) << 16);
    }
    *(uint4*)op = o;
}

// ============ mid-phase MFMA linear, BM=64 x BN=64 (round-9 proven) ============
template<bool BIAS>
__global__ __launch_bounds__(256) void lin64_k(
    const float* __restrict__ A1, int lda1, int KA1,
    const float* __restrict__ A2, int lda2,
    const bf16u* __restrict__ WT, int ldw,
    const float* __restrict__ bias,
    float* __restrict__ C, int ldc, int K)
{
    __shared__ bf16u As[64][40];
    __shared__ bf16u Bs[64][40];
    const int tid = threadIdx.x;
    const int lane = tid & 63, w = tid >> 6;
    const int m0 = blockIdx.x * 64;
    const int col0 = blockIdx.y * 64;
    const int ar = tid >> 2, kq8 = (tid & 3) * 8;
    const int lr = lane & 15, lk = (lane >> 4) * 8;

    f32x4 acc[4];
    const f32x4 zf = {0.f, 0.f, 0.f, 0.f};
    #pragma unroll
    for (int j = 0; j < 4; ++j) acc[j] = zf;

    for (int k0 = 0; k0 < K; k0 += 32) {
        const float* src = (k0 < KA1)
            ? (A1 + (size_t)(m0 + ar) * lda1 + k0 + kq8)
            : (A2 + (size_t)(m0 + ar) * lda2 + (k0 - KA1) + kq8);
        float4 f0 = *(const float4*)src;
        float4 f1 = *(const float4*)(src + 4);
        ushort4 s0, s1;
        s0.x = f2b(f0.x); s0.y = f2b(f0.y); s0.z = f2b(f0.z); s0.w = f2b(f0.w);
        s1.x = f2b(f1.x); s1.y = f2b(f1.y); s1.z = f2b(f1.z); s1.w = f2b(f1.w);
        *(ushort4*)&As[ar][kq8] = s0;
        *(ushort4*)&As[ar][kq8 + 4] = s1;
        *(uint4*)&Bs[ar][kq8] = *(const uint4*)(WT + (size_t)(col0 + ar) * ldw + k0 + kq8);
        __syncthreads();

        short8v a = *(const short8v*)&As[w * 16 + lr][lk];
        short8v b[4];
        #pragma unroll
        for (int nf = 0; nf < 4; ++nf)
            b[nf] = *(const short8v*)&Bs[nf * 16 + lr][lk];
        #pragma unroll
        for (int nf = 0; nf < 4; ++nf)
            acc[nf] = __builtin_amdgcn_mfma_f32_16x16x32_bf16(a, b[nf], acc[nf], 0, 0, 0);
        __syncthreads();
    }

    const int rbase = (lane >> 4) * 4;
    #pragma unroll
    for (int nf = 0; nf < 4; ++nf) {
        const int col = col0 + nf * 16 + lr;
        #pragma unroll
        for (int r = 0; r < 4; ++r) {
            const int row = m0 + w * 16 + rbase + r;
            float v = acc[nf][r];
            if (BIAS) v += bias[col];
            C[(size_t)row * ldc + col] = v;
        }
    }
}

__device__ __forceinline__ float sigm(float x) { return 1.f / (1.f + expf(-x)); }

// ============ fused LSTM gates GEMM + pointwise ============
// gates = [q_star | h] @ WT^T + b (K=768, N=1024); each block: 16-wide d-slice x 4 gates.
// grid = (M/64, 16). Epilogue computes c,h into PING-PONG buffers (no race).
__global__ __launch_bounds__(256) void gates_lstm_k(
    const float* __restrict__ QSTAR,  // [M,512]
    const float* __restrict__ Hc,     // [M,256]
    const float* __restrict__ Cc,     // [M,256]
    const bf16u* __restrict__ WT,     // [1024][768]
    const float* __restrict__ bias,   // [1024]
    float* __restrict__ Hn,
    float* __restrict__ Cn,
    int M)
{
    __shared__ bf16u As[64][40];
    __shared__ bf16u Bs[64][40];
    const int tid = threadIdx.x;
    const int lane = tid & 63, w = tid >> 6;      // 4 waves, 16 rows each
    const int m0 = blockIdx.x * 64;
    const int db = blockIdx.y;                    // d-slice [db*16, +16)
    const int ar = tid >> 2, q8 = (tid & 3) * 8;
    const int lr = lane & 15, lk = (lane >> 4) * 8;

    f32x4 acc[4];                                 // one per gate
    const f32x4 zf = {0.f, 0.f, 0.f, 0.f};
    #pragma unroll
    for (int g = 0; g < 4; ++g) acc[g] = zf;

    for (int k0 = 0; k0 < 768; k0 += 32) {
        const float* src = (k0 < 512)
            ? QSTAR + (size_t)(m0 + ar) * 512 + k0 + q8
            : Hc + (size_t)(m0 + ar) * 256 + (k0 - 512) + q8;
        float4 f0 = *(const float4*)src;
        float4 f1 = *(const float4*)(src + 4);
        ushort4 s0, s1;
        s0.x = f2b(f0.x); s0.y = f2b(f0.y); s0.z = f2b(f0.z); s0.w = f2b(f0.w);
        s1.x = f2b(f1.x); s1.y = f2b(f1.y); s1.z = f2b(f1.z); s1.w = f2b(f1.w);
        *(ushort4*)&As[ar][q8] = s0;
        *(ushort4*)&As[ar][q8 + 4] = s1;
        // B: 64 WT rows = 4 gates x 16 cols; thread t: row rho=t>>2, 16B chunk q8
        {
            int rho = tid >> 2;
            int g = rho >> 4, cn = rho & 15;
            *(uint4*)&Bs[rho][q8] =
                *(const uint4*)(WT + (size_t)(g * 256 + db * 16 + cn) * 768 + k0 + q8);
        }
        __syncthreads();
        short8v a = *(const short8v*)&As[w * 16 + lr][lk];
        #pragma unroll
        for (int g = 0; g < 4; ++g) {
            short8v b = *(const short8v*)&Bs[g * 16 + lr][lk];
            acc[g] = __builtin_amdgcn_mfma_f32_16x16x32_bf16(a, b, acc[g], 0, 0, 0);
        }
        __syncthreads();
    }

    const int rbase = (lane >> 4) * 4;
    const int d = db * 16 + lr;
    const float bi = bias[d], bf = bias[256 + d], bg = bias[512 + d], bo = bias[768 + d];
    #pragma unroll
    for (int r = 0; r < 4; ++r) {
        const int row = m0 + w * 16 + rbase + r;
        float i_ = acc[0][r] + bi;
        float f_ = acc[1][r] + bf;
        float g_ = acc[2][r] + bg;
        float o_ = acc[3][r] + bo;
        float cv = sigm(f_) * Cc[(size_t)row * 256 + d] + sigm(i_) * tanhf(g_);
        Cn[(size_t)row * 256 + d] = cv;
        Hn[(size_t)row * 256 + d] = sigm(o_) * tanhf(cv);
    }
}

// ---------------- prep kernels ----------------
__global__ __launch_bounds__(256) void prep_wt_k(const float* __restrict__ W,
                                                 bf16u* __restrict__ WT, int K, int KP)
{
    int idx = blockIdx.x * 256 + threadIdx.x;
    if (idx >= 256 * KP) return;
    int n = idx / KP, k = idx - n * KP;
    WT[idx] = (k < K) ? f2b(W[(size_t)k * H + n]) : (bf16u)0;
}

__global__ __launch_bounds__(256) void prep_wto_k(const float* __restrict__ Wo,
                                                  bf16u* __restrict__ WT)
{
    int idx = blockIdx.x * 256 + threadIdx.x;
    if (idx >= 256 * 416) return;
    int n = idx / 416, k = idx - n * 416;
    float v = 0.f;
    if (k < ATOM_FDIM) v = Wo[(size_t)k * H + n];
    else if (k >= 160) v = Wo[(size_t)(ATOM_FDIM + k - 160) * H + n];
    WT[idx] = f2b(v);
}

// merged mid-phase weight prep (single dispatch)
#define SZ_WTG   786432    // [1024][768]
#define SZ_WTNC  131072    // [256][512]
#define SZ_WTPQS 196608    // [768][256]
#define SZ_WTN1  262144    // [256][1024]
#define SZ_WTGC  131072    // [256][512]
__global__ __launch_bounds__(256) void prep_mid_k(
    const float* __restrict__ Wih_n, const float* __restrict__ Whh_n,
    const float* __restrict__ Wih_g, const float* __restrict__ Whh_g,
    const float* __restrict__ ncW,  const float* __restrict__ Wnn0,
    const float* __restrict__ Wnn0s, const float* __restrict__ Wnn1,
    const float* __restrict__ gcW,  const float* __restrict__ b_nn0s,
    bf16u* __restrict__ WTG_N, bf16u* __restrict__ WTG_G,
    bf16u* __restrict__ WT_NC, bf16u* __restrict__ WT_PQS,
    bf16u* __restrict__ WT_N1, bf16u* __restrict__ WT_GC,
    float* __restrict__ BIAS_PQS)
{
    int idx = blockIdx.x * 256 + threadIdx.x;
    if (idx < SZ_WTG) {
        int n = idx / 768, k = idx - n * 768;
        WTG_N[idx] = f2b(k < 512 ? Wih_n[(size_t)n * 512 + k] : Whh_n[(size_t)n * 256 + (k - 512)]);
        return;
    }
    idx -= SZ_WTG;
    if (idx < SZ_WTG) {
        int n = idx / 768, k = idx - n * 768;
        WTG_G[idx] = f2b(k < 512 ? Wih_g[(size_t)n * 512 + k] : Whh_g[(size_t)n * 256 + (k - 512)]);
        return;
    }
    idx -= SZ_WTG;
    if (idx < SZ_WTNC) {
        int n = idx / 512, k = idx - n * 512;
        WT_NC[idx] = f2b(ncW[(size_t)k * 256 + n]);
        return;
    }
    idx -= SZ_WTNC;
    if (idx < SZ_WTPQS) {
        int n = idx / 256, k = idx - n * 256;
        float v;
        if (n < 256)      v = Wnn0[(size_t)k * 256 + n];
        else if (n < 512) v = Wnn0[(size_t)(256 + k) * 256 + (n - 256)];
        else              v = Wnn0s[(size_t)k * 256 + (n - 512)];
        WT_PQS[idx] = f2b(v);
        return;
    }
    idx -= SZ_WTPQS;
    if (idx < SZ_WTN1) {
        int n = idx / 1024, k = idx - n * 1024;
        WT_N1[idx] = f2b(Wnn1[(size_t)k * 256 + n]);
        return;
    }
    idx -= SZ_WTN1;
    if (idx < SZ_WTGC) {
        int n = idx / 512, k = idx - n * 512;
        WT_GC[idx] = f2b(gcW[(size_t)k * 256 + n]);
        return;
    }
    idx -= SZ_WTGC;
    if (idx < 768) BIAS_PQS[idx] = (idx < 512) ? 0.f : b_nn0s[idx - 512];
}
#define PREP_MID_TOTAL (2 * SZ_WTG + SZ_WTNC + SZ_WTPQS + SZ_WTN1 + SZ_WTGC + 768)

__global__ __launch_bounds__(256) void prep_feat16_k(const float* __restrict__ F,
                                                     bf16u* __restrict__ O,
                                                     int rows, int K)
{
    int idx = blockIdx.x * 256 + threadIdx.x;
    if (idx >= rows * 160) return;
    int r = idx / 160, c = idx - r * 160;
    O[idx] = (c < K) ? f2b(F[(size_t)r * K + c]) : (bf16u)0;
}

// ---------------- small kernels ----------------
__global__ __launch_bounds__(256) void gather6_bf16_k(const bf16u* __restrict__ msg,
                                                      const int* __restrict__ a2b,
                                                      bf16u* __restrict__ outb)
{
    int idx = blockIdx.x * 256 + threadIdx.x;
    if (idx >= N_ATOMS * (H / 8)) return;
    int na = idx >> 5, c = idx & 31;
    const int* nb = a2b + (size_t)na * MAX_NB;
    float s[8] = {0.f, 0.f, 0.f, 0.f, 0.f, 0.f, 0.f, 0.f};
    #pragma unroll
    for (int j = 0; j < MAX_NB; ++j) {
        uint4 u = *(const uint4*)(msg + (size_t)nb[j] * H + c * 8);
        s[0] += b2f((bf16u)(u.x & 0xFFFFu)); s[1] += b2f((bf16u)(u.x >> 16));
        s[2] += b2f((bf16u)(u.y & 0xFFFFu)); s[3] += b2f((bf16u)(u.y >> 16));
        s[4] += b2f((bf16u)(u.z & 0xFFFFu)); s[5] += b2f((bf16u)(u.z >> 16));
        s[6] += b2f((bf16u)(u.w & 0xFFFFu)); s[7] += b2f((bf16u)(u.w >> 16));
    }
    uint4 o;
    o.x = (unsigned int)f2b(s[0]) | ((unsigned int)f2b(s[1]) << 16);
    o.y = (unsigned int)f2b(s[2]) | ((unsigned int)f2b(s[3]) << 16);
    o.z = (unsigned int)f2b(s[4]) | ((unsigned int)f2b(s[5]) << 16);
    o.w = (unsigned int)f2b(s[6]) | ((unsigned int)f2b(s[7]) << 16);
    *(uint4*)(outb + (size_t)na * H + c * 8) = o;
}

__global__ __launch_bounds__(256) void zero_f32_k(float* __restrict__ p, int n)
{
    int idx = blockIdx.x * 256 + threadIdx.x;
    if (idx < n) p[idx] = 0.f;
}

// feat bf16 (BF16F) or f32; h/q_star f32
template<bool BF16F>
__global__ __launch_bounds__(256) void s2s_attn_k(const void* __restrict__ featv,
                                                  const float* __restrict__ h,
                                                  float* __restrict__ q_star, int Nn)
{
    int m = blockIdx.x;
    int t = threadIdx.x;
    int lane = t & 63, wave = t >> 6;
    __shared__ float sc[32];
    const bf16u* fb = (const bf16u*)featv;
    const float* ff = (const float*)featv;
    const size_t fbase = (size_t)m * Nn * H;
    const float* hm = h + (size_t)m * H;
    for (int n = wave; n < Nn; n += 4) {
        float p = 0.f;
        if (BF16F) {
            ushort4 u = *(const ushort4*)(fb + fbase + (size_t)n * H + lane * 4);
            const float4 h4 = *(const float4*)(hm + lane * 4);
            p = b2f(u.x) * h4.x + b2f(u.y) * h4.y + b2f(u.z) * h4.z + b2f(u.w) * h4.w;
        } else {
            const float* fr = ff + fbase + (size_t)n * H;
            #pragma unroll
            for (int u = 0; u < 4; ++u) p += fr[lane * 4 + u] * hm[lane * 4 + u];
        }
        #pragma unroll
        for (int o = 32; o >= 1; o >>= 1) p += __shfl_xor(p, o);
        if (lane == 0) sc[n] = p;
    }
    __syncthreads();
    float mx = -1e30f;
    for (int n = 0; n < Nn; ++n) mx = fmaxf(mx, sc[n]);
    float ssum = 0.f, r = 0.f;
    for (int n = 0; n < Nn; ++n) {
        float a = expf(sc[n] - mx);
        ssum += a;
        float fv = BF16F ? b2f(fb[fbase + (size_t)n * H + t]) : ff[fbase + (size_t)n * H + t];
        r += a * fv;
    }
    r /= ssum;
    q_star[(size_t)m * (2 * H) + t] = hm[t];
    q_star[(size_t)m * (2 * H) + H + t] = r;
}

// X[b,s1,s2,:] from packed PQS [2048][768]: P = +0, Q = +256, SO = +512
__global__ __launch_bounds__(256) void build_x_k(const float* __restrict__ PQS,
                                                 const float* __restrict__ b0,
                                                 float* __restrict__ X)
{
    int idx = blockIdx.x * 256 + threadIdx.x;
    if (idx >= B_RXN * S_STEPS * S_STEPS * H) return;
    int d  = idx & 255;
    int s2 = (idx >> 8) & 3;
    int s1 = (idx >> 10) & 3;
    int b  = idx >> 12;
    float v;
    if (s1 == s2) v = PQS[((size_t)(b * S_STEPS + s1)) * 768 + 512 + d];
    else v = PQS[((size_t)(b * S_STEPS + s1)) * 768 + d]
           + PQS[((size_t)(b * S_STEPS + s2)) * 768 + 256 + d] + b0[d];
    X[idx] = v;
}

// ---------------- launch ----------------
extern "C" void kernel_launch(void* const* d_in, const int* in_sizes, int n_in,
                              void* d_out, int out_size, void* d_ws, size_t ws_size,
                              hipStream_t stream)
{
    const float* f_atoms   = (const float*)d_in[0];
    const float* f_bonds   = (const float*)d_in[1];
    const int*   a2b       = (const int*)d_in[2];
    const int*   b2a       = (const int*)d_in[3];
    const int*   b2revb    = (const int*)d_in[4];
    const float* W_i       = (const float*)d_in[5];
    const float* W_h       = (const float*)d_in[6];
    const float* W_o       = (const float*)d_in[7];
    const float* b_o       = (const float*)d_in[8];
    const float* W_nn0     = (const float*)d_in[9];
    const float* b_nn0     = (const float*)d_in[10];
    const float* W_nn0s    = (const float*)d_in[11];
    const float* b_nn0s    = (const float*)d_in[12];
    const float* W_nn1     = (const float*)d_in[13];
    const float* b_nn1     = (const float*)d_in[14];
    const float* lstm_n_Wih = (const float*)d_in[15];
    const float* lstm_n_Whh = (const float*)d_in[16];
    const float* lstm_n_b   = (const float*)d_in[17];
    const float* node_cond_W = (const float*)d_in[18];
    const float* node_cond_b = (const float*)d_in[19];
    const float* lstm_g_Wih = (const float*)d_in[20];
    const float* lstm_g_Whh = (const float*)d_in[21];
    const float* lstm_g_b   = (const float*)d_in[22];
    const float* graph_cond_W = (const float*)d_in[23];
    const float* graph_cond_b = (const float*)d_in[24];
    float* out = (float*)d_out;

    // ---- workspace layout (~235 MB) ----
    const size_t SZB = (size_t)NBP1 * H * sizeof(bf16u);    // 67,109,376 B
    char* base = (char*)d_ws;
    bf16u* INP  = (bf16u*)(base);                            // [NBP1,H]
    bf16u* MSG  = (bf16u*)(base + SZB);                      // [NBP1,H]
    bf16u* MW   = (bf16u*)(base + 2 * SZB);                  // [NBP1,H]
    bf16u* AMSG = (bf16u*)(base + 3 * SZB);                  // [N_ATOMS,H]
    bf16u* WT_I = (bf16u*)(base + 3 * SZB + 33554432);       // [256][160]
    bf16u* WT_H = (bf16u*)(base + 3 * SZB + 33636352);       // [256][256]
    bf16u* WT_O = (bf16u*)(base + 3 * SZB + 33767424);       // [256][416]
    // aliases:
    bf16u* FB16 = MW;                                        // before 1st MW
    bf16u* FA16 = MW;                                        // after last combine
    bf16u* ATOMH16 = (bf16u*)(base);                         // bf16 feat, alias INP (dead)
    float* SMALL = (float*)(base + SZB);                     // f32 scratch, alias MSG (dead)
    float* HN     = SMALL + 2097152;                         // [2048,256] (ping A)
    float* CN     = SMALL + 2621440;                         // [2048,256] (ping A)
    float* QSTARN = SMALL + 3145728;                         // [2048,512]
    float* MOL    = SMALL + 4194304;                         // [2048,256]
    float* PQS    = SMALL + 4718592;                         // [2048,768]
    float* XBUF   = SMALL + 6291456;                         // [8192,256]
    float* STEPS  = SMALL + 8388608;                         // [2048,256]
    float* HG     = SMALL + 8912896;                         // [512,256] (ping A)
    float* CG     = SMALL + 9043968;                         // [512,256] (ping A)
    float* QSTARG = SMALL + 9175040;                         // [512,512]
    float* HN2    = SMALL + 10485760;                        // [2048,256] (pong B)
    float* CN2    = SMALL + 11010048;                        // [2048,256] (pong B)
    float* HG2    = SMALL + 11534336;                        // [512,256]  (pong B)
    float* CG2    = SMALL + 11665408;                        // [512,256]  (pong B)
    char* sm2 = base + 2 * SZB + 25165824;                   // MW dead zone
    bf16u* WTG_N   = (bf16u*)(sm2);                  // [1024][768]
    bf16u* WTG_G   = (bf16u*)(sm2 + 1572864);        // [1024][768]
    bf16u* WT_NC   = (bf16u*)(sm2 + 3145728);        // [256][512]
    bf16u* WT_PQS  = (bf16u*)(sm2 + 3407872);        // [768][256]
    bf16u* WT_N1   = (bf16u*)(sm2 + 3801088);        // [256][1024]
    bf16u* WT_GC   = (bf16u*)(sm2 + 4325376);        // [256][512]
    float* BIAS_PQS = (float*)(sm2 + 4587520);       // [768]

    dim3 blk(256), blk5(512);
    const int MB_BOND = (NBP1 + 127) / 128;   // 1025
    const int MB_ATOM = N_ATOMS / 128;        // 512
    const int G_GATH = (N_ATOMS * (H / 8) + 255) / 256;
    const int G_COMB = (NBP1 * 32 + 255) / 256;

    // 0. weight + input prep
    prep_wt_k<<<(256 * 160 + 255) / 256, blk, 0, stream>>>(W_i, WT_I, BOND_FDIM, 160);
    prep_wt_k<<<(256 * 256 + 255) / 256, blk, 0, stream>>>(W_h, WT_H, H, 256);
    prep_wto_k<<<(256 * 416 + 255) / 256, blk, 0, stream>>>(W_o, WT_O);
    prep_feat16_k<<<(int)(((size_t)NBP1 * 160 + 255) / 256), blk, 0, stream>>>(
        f_bonds, FB16, NBP1, BOND_FDIM);

    // 1. INP = FB16 @ W_i
    dense_gemm_k<0, false><<<MB_BOND, blk5, 0, stream>>>(
        FB16, nullptr, WT_I, nullptr, INP, NBP1);

    // 2. depth loop
    dense_gemm_k<1, true><<<MB_BOND, blk5, 0, stream>>>(
        INP, nullptr, WT_H, nullptr, MW, NBP1);
    gather6_bf16_k<<<G_GATH, blk, 0, stream>>>(MW, a2b, AMSG);
    combine_k<<<G_COMB, blk, 0, stream>>>(INP, AMSG, MW, b2a, b2revb, MSG);
    dense_gemm_k<1, false><<<MB_BOND, blk5, 0, stream>>>(
        MSG, nullptr, WT_H, nullptr, MW, NBP1);
    gather6_bf16_k<<<G_GATH, blk, 0, stream>>>(MW, a2b, AMSG);
    combine_k<<<G_COMB, blk, 0, stream>>>(INP, AMSG, MW, b2a, b2revb, MSG);

    // 3. nei = gather6(final MSG)
    gather6_bf16_k<<<G_GATH, blk, 0, stream>>>(MSG, a2b, AMSG);

    // 3b. packed f_atoms + merged mid-phase weight prep (MW region dead)
    prep_feat16_k<<<(N_ATOMS * 160 + 255) / 256, blk, 0, stream>>>(
        f_atoms, FA16, N_ATOMS, ATOM_FDIM);
    prep_mid_k<<<(PREP_MID_TOTAL + 255) / 256, blk, 0, stream>>>(
        lstm_n_Wih, lstm_n_Whh, lstm_g_Wih, lstm_g_Whh,
        node_cond_W, W_nn0, W_nn0s, W_nn1, graph_cond_W, b_nn0s,
        WTG_N, WTG_G, WT_NC, WT_PQS, WT_N1, WT_GC, BIAS_PQS);

    // 4. atom_h = relu([f_atoms, nei] @ W_o + b_o) -> ATOMH16 bf16
    dense_gemm_k<2, false><<<MB_ATOM, blk5, 0, stream>>>(
        FA16, AMSG, WT_O, b_o, ATOMH16, N_ATOMS);

    // 5. node Set2Set over [2048, 32, 256]
    zero_f32_k<<<(2097152 + 255) / 256, blk, 0, stream>>>(HN, 2097152);  // HN,CN,QSTARN
    {
        float *hc = HN, *cc = CN, *hn = HN2, *cn = CN2;
        for (int it = 0; it < N_ITERS; ++it) {
            gates_lstm_k<<<dim3(N_MOLS / 64, 16), blk, 0, stream>>>(
                QSTARN, hc, cc, WTG_N, lstm_n_b, hn, cn, N_MOLS);
            s2s_attn_k<true><<<N_MOLS, blk, 0, stream>>>(ATOMH16, hn, QSTARN, ATOMS_PER_MOL);
            float* t;
            t = hc; hc = hn; hn = t;
            t = cc; cc = cn; cn = t;
        }
    }
    lin64_k<true><<<dim3(N_MOLS / 64, 4), blk, 0, stream>>>(
        QSTARN, 2 * H, 2 * H, QSTARN, 2 * H, WT_NC, 2 * H, node_cond_b, MOL, H, 2 * H);

    // 6. NN attention over steps (fused P|Q|SO GEMM)
    lin64_k<true><<<dim3(N_MOLS / 64, 12), blk, 0, stream>>>(
        MOL, H, H, MOL, H, WT_PQS, H, BIAS_PQS, PQS, 3 * H, H);
    build_x_k<<<(B_RXN * 16 * H) / 256, blk, 0, stream>>>(PQS, b_nn0, XBUF);
    lin64_k<true><<<dim3(N_MOLS / 64, 4), blk, 0, stream>>>(
        XBUF, S_STEPS * H, S_STEPS * H, XBUF, S_STEPS * H, WT_N1, S_STEPS * H, b_nn1,
        STEPS, H, S_STEPS * H);

    // 7. graph Set2Set over [512, 4, 256]
    zero_f32_k<<<(524288 + 255) / 256, blk, 0, stream>>>(HG, 524288);    // HG,CG,QSTARG
    {
        float *hc = HG, *cc = CG, *hn = HG2, *cn = CG2;
        for (int it = 0; it < N_ITERS; ++it) {
            gates_lstm_k<<<dim3(B_RXN / 64, 16), blk, 0, stream>>>(
                QSTARG, hc, cc, WTG_G, lstm_g_b, hn, cn, B_RXN);
            s2s_attn_k<false><<<B_RXN, blk, 0, stream>>>(STEPS, hn, QSTARG, S_STEPS);
            float* t;
            t = hc; hc = hn; hn = t;
            t = cc; cc = cn; cn = t;
        }
    }

    // 8. out
    lin64_k<true><<<dim3(B_RXN / 64, 4), blk, 0, stream>>>(
        QSTARG, 2 * H, 2 * H, QSTARG, 2 * H, WT_GC, 2 * H, graph_cond_b, out, H, 2 * H);
}

// Round 12
// 611.724 us; speedup vs baseline: 2.1366x; 1.1065x over previous
//
#include <hip/hip_runtime.h>
#include <math.h>

// ---------------- problem constants ----------------
#define H 256
#define S_STEPS 4
#define B_RXN 512
#define N_MOLS 2048          // B*S
#define ATOMS_PER_MOL 32
#define N_ATOMS 65536        // N_MOLS*32
#define N_BONDS 131072
#define NBP1 131073          // N_BONDS+1
#define MAX_NB 6
#define ATOM_FDIM 133
#define BOND_FDIM 147
#define DEPTH 3
#define N_ITERS 3

typedef unsigned short bf16u;
typedef __attribute__((ext_vector_type(8))) short short8v;  // 8 bf16 = 4 VGPR
typedef __attribute__((ext_vector_type(4))) float f32x4;

__device__ __forceinline__ float b2f(bf16u u) {
    union { unsigned int i; float f; } c; c.i = ((unsigned int)u) << 16; return c.f;
}
__device__ __forceinline__ bf16u f2b(float f) {
    union { float f; unsigned int i; } c; c.f = f;
    unsigned int i = c.i;
    return (bf16u)((i + 0x7FFFu + ((i >> 16) & 1u)) >> 16);   // RNE
}
__device__ __forceinline__ unsigned int relu2bf(unsigned int w) {
    unsigned int lo = w & 0xFFFFu, hi = w >> 16;
    if (lo & 0x8000u) lo = 0u;
    if (hi & 0x8000u) hi = 0u;
    return lo | (hi << 16);
}

// ============ dense MFMA GEMM (bond/atom): BM=128, 512 thr / 8 waves (round-10 proven) ======
// MODE 0 (WI):   A = FB16 [M,160];              epi: INP = bf16(acc)
// MODE 1 (MW):   A = msg-source [M,256] (opt. relu in staging); epi: MW = bf16(acc)
// MODE 2 (ATOM): A = [FA16 160 | AMSG 256] (KP=416); epi: bf16 relu(acc+bias)
template<int MODE, bool RELUA>
__global__ __launch_bounds__(512) void dense_gemm_k(
    const bf16u* __restrict__ A1,
    const bf16u* __restrict__ A2,     // MODE2 only
    const bf16u* __restrict__ WT,     // [256][KP] bf16
    const float* __restrict__ bias,   // MODE2 only
    bf16u* __restrict__ outb,
    int M)
{
    constexpr int KP = (MODE == 0) ? 160 : ((MODE == 1) ? 256 : 416);
    __shared__ bf16u As[128][40];
    __shared__ bf16u Bs[256][40];

    const int tid = threadIdx.x;
    const int lane = tid & 63, w = tid >> 6;      // 8 waves
    const int wr = w >> 2, wc = w & 3;            // 2 x 4 wave grid
    const int m0 = blockIdx.x * 128;
    const int ar = tid >> 2, q8 = (tid & 3) * 8;  // A stage: row, k-chunk
    const int br = tid >> 1, bh = (tid & 1) * 16; // B stage: row, k-half
    const int arow = m0 + ar;
    const bool rok = arow < M;
    const int lr = lane & 15, lk = (lane >> 4) * 8;
    const uint4 z4 = {0u, 0u, 0u, 0u};

    f32x4 acc[4][4];
    const f32x4 zf = {0.f, 0.f, 0.f, 0.f};
    #pragma unroll
    for (int i = 0; i < 4; ++i)
        #pragma unroll
        for (int j = 0; j < 4; ++j) acc[i][j] = zf;

    for (int k0 = 0; k0 < KP; k0 += 32) {
        // ---- stage A: one uint4 per thread (contiguous) ----
        const int kc = k0 + q8;
        uint4 va;
        if (MODE == 2) {
            va = (kc < 160) ? *(const uint4*)(A1 + (size_t)arow * 160 + kc)
                            : *(const uint4*)(A2 + (size_t)arow * 256 + (kc - 160));
        } else {
            constexpr int LDA = (MODE == 0) ? 160 : 256;
            va = rok ? *(const uint4*)(A1 + (size_t)arow * LDA + kc) : z4;
        }
        if (RELUA) {
            va.x = relu2bf(va.x); va.y = relu2bf(va.y);
            va.z = relu2bf(va.z); va.w = relu2bf(va.w);
        }
        *(uint4*)&As[ar][q8] = va;
        // ---- stage B: 2 uint4 per thread ----
        {
            const bf16u* bp = WT + (size_t)br * KP + k0 + bh;
            uint4 b0 = *(const uint4*)(bp);
            uint4 b1 = *(const uint4*)(bp + 8);
            *(uint4*)&Bs[br][bh] = b0;
            *(uint4*)&Bs[br][bh + 8] = b1;
        }
        __syncthreads();

        short8v a[4], b[4];
        #pragma unroll
        for (int mf = 0; mf < 4; ++mf)
            a[mf] = *(const short8v*)&As[wr * 64 + mf * 16 + lr][lk];
        #pragma unroll
        for (int nf = 0; nf < 4; ++nf)
            b[nf] = *(const short8v*)&Bs[wc * 64 + nf * 16 + lr][lk];
        #pragma unroll
        for (int mf = 0; mf < 4; ++mf)
            #pragma unroll
            for (int nf = 0; nf < 4; ++nf)
                acc[mf][nf] = __builtin_amdgcn_mfma_f32_16x16x32_bf16(
                    a[mf], b[nf], acc[mf][nf], 0, 0, 0);
        __syncthreads();
    }

    const int rbase = (lane >> 4) * 4;
    #pragma unroll
    for (int mf = 0; mf < 4; ++mf) {
        #pragma unroll
        for (int nf = 0; nf < 4; ++nf) {
            const int col = wc * 64 + nf * 16 + lr;
            #pragma unroll
            for (int r = 0; r < 4; ++r) {
                const int row = m0 + wr * 64 + mf * 16 + rbase + r;
                if (row >= M) continue;
                float v = acc[mf][nf][r];
                const size_t off = (size_t)row * H + col;
                if (MODE == 2) {
                    v += bias[col];
                    outb[off] = f2b(fmaxf(v, 0.f));
                } else {
                    outb[off] = f2b(v);
                }
            }
        }
    }
}

// ---- combine: msg[b] = relu(inp[b] + AP[b2a[b]] - MW[b2revb[b]]), row 0 = 0 ----
__global__ __launch_bounds__(256) void combine_k(
    const bf16u* __restrict__ inp, const bf16u* __restrict__ AP,
    const bf16u* __restrict__ MW,
    const int* __restrict__ b2a, const int* __restrict__ b2revb,
    bf16u* __restrict__ msg)
{
    int idx = blockIdx.x * 256 + threadIdx.x;
    if (idx >= NBP1 * 32) return;
    int b = idx >> 5, c = (idx & 31) * 8;
    bf16u* op = msg + (size_t)b * H + c;
    if (b == 0) {
        *(uint4*)op = make_uint4(0u, 0u, 0u, 0u);
        return;
    }
    int a = b2a[b], rb = b2revb[b];
    uint4 ui = *(const uint4*)(inp + (size_t)b * H + c);
    uint4 up = *(const uint4*)(AP + (size_t)a * H + c);
    uint4 um = *(const uint4*)(MW + (size_t)rb * H + c);
    uint4 o;
    unsigned int* pi = &ui.x; unsigned int* pp = &up.x;
    unsigned int* pm = &um.x; unsigned int* po = &o.x;
    #pragma unroll
    for (int t = 0; t < 4; ++t) {
        float lo = b2f((bf16u)(pi[t] & 0xFFFFu)) + b2f((bf16u)(pp[t] & 0xFFFFu))
                 - b2f((bf16u)(pm[t] & 0xFFFFu));
        float hi = b2f((bf16u)(pi[t] >> 16)) + b2f((bf16u)(pp[t] >> 16))
                 - b2f((bf16u)(pm[t] >> 16));
        lo = fmaxf(lo, 0.f); hi = fmaxf(hi, 0.f);
        po[t] = (unsigned int)f2b(lo) | ((unsigned int)f2b(hi) << 16);
    }
    *(uint4*)op = o;
}

// ============ mid-phase MFMA linear, BM=64 x BN=64 (round-9 proven) ============
template<bool BIAS>
__global__ __launch_bounds__(256) void lin64_k(
    const float* __restrict__ A1, int lda1, int KA1,
    const float* __restrict__ A2, int lda2,
    const bf16u* __restrict__ WT, int ldw,
    const float* __restrict__ bias,
    float* __restrict__ C, int ldc, int K)
{
    __shared__ bf16u As[64][40];
    __shared__ bf16u Bs[64][40];
    const int tid = threadIdx.x;
    const int lane = tid & 63, w = tid >> 6;
    const int m0 = blockIdx.x * 64;
    const int col0 = blockIdx.y * 64;
    const int ar = tid >> 2, kq8 = (tid & 3) * 8;
    const int lr = lane & 15, lk = (lane >> 4) * 8;

    f32x4 acc[4];
    const f32x4 zf = {0.f, 0.f, 0.f, 0.f};
    #pragma unroll
    for (int j = 0; j < 4; ++j) acc[j] = zf;

    for (int k0 = 0; k0 < K; k0 += 32) {
        const float* src = (k0 < KA1)
            ? (A1 + (size_t)(m0 + ar) * lda1 + k0 + kq8)
            : (A2 + (size_t)(m0 + ar) * lda2 + (k0 - KA1) + kq8);
        float4 f0 = *(const float4*)src;
        float4 f1 = *(const float4*)(src + 4);
        ushort4 s0, s1;
        s0.x = f2b(f0.x); s0.y = f2b(f0.y); s0.z = f2b(f0.z); s0.w = f2b(f0.w);
        s1.x = f2b(f1.x); s1.y = f2b(f1.y); s1.z = f2b(f1.z); s1.w = f2b(f1.w);
        *(ushort4*)&As[ar][kq8] = s0;
        *(ushort4*)&As[ar][kq8 + 4] = s1;
        *(uint4*)&Bs[ar][kq8] = *(const uint4*)(WT + (size_t)(col0 + ar) * ldw + k0 + kq8);
        __syncthreads();

        short8v a = *(const short8v*)&As[w * 16 + lr][lk];
        short8v b[4];
        #pragma unroll
        for (int nf = 0; nf < 4; ++nf)
            b[nf] = *(const short8v*)&Bs[nf * 16 + lr][lk];
        #pragma unroll
        for (int nf = 0; nf < 4; ++nf)
            acc[nf] = __builtin_amdgcn_mfma_f32_16x16x32_bf16(a, b[nf], acc[nf], 0, 0, 0);
        __syncthreads();
    }

    const int rbase = (lane >> 4) * 4;
    #pragma unroll
    for (int nf = 0; nf < 4; ++nf) {
        const int col = col0 + nf * 16 + lr;
        #pragma unroll
        for (int r = 0; r < 4; ++r) {
            const int row = m0 + w * 16 + rbase + r;
            float v = acc[nf][r];
            if (BIAS) v += bias[col];
            C[(size_t)row * ldc + col] = v;
        }
    }
}

__device__ __forceinline__ float sigm(float x) { return 1.f / (1.f + expf(-x)); }

// ============ fused LSTM gates GEMM + pointwise (round-11 proven) ============
__global__ __launch_bounds__(256) void gates_lstm_k(
    const float* __restrict__ QSTAR,  // [M,512]
    const float* __restrict__ Hc,     // [M,256]
    const float* __restrict__ Cc,     // [M,256]
    const bf16u* __restrict__ WT,     // [1024][768]
    const float* __restrict__ bias,   // [1024]
    float* __restrict__ Hn,
    float* __restrict__ Cn,
    int M)
{
    __shared__ bf16u As[64][40];
    __shared__ bf16u Bs[64][40];
    const int tid = threadIdx.x;
    const int lane = tid & 63, w = tid >> 6;      // 4 waves, 16 rows each
    const int m0 = blockIdx.x * 64;
    const int db = blockIdx.y;                    // d-slice [db*16, +16)
    const int ar = tid >> 2, q8 = (tid & 3) * 8;
    const int lr = lane & 15, lk = (lane >> 4) * 8;

    f32x4 acc[4];                                 // one per gate
    const f32x4 zf = {0.f, 0.f, 0.f, 0.f};
    #pragma unroll
    for (int g = 0; g < 4; ++g) acc[g] = zf;

    for (int k0 = 0; k0 < 768; k0 += 32) {
        const float* src = (k0 < 512)
            ? QSTAR + (size_t)(m0 + ar) * 512 + k0 + q8
            : Hc + (size_t)(m0 + ar) * 256 + (k0 - 512) + q8;
        float4 f0 = *(const float4*)src;
        float4 f1 = *(const float4*)(src + 4);
        ushort4 s0, s1;
        s0.x = f2b(f0.x); s0.y = f2b(f0.y); s0.z = f2b(f0.z); s0.w = f2b(f0.w);
        s1.x = f2b(f1.x); s1.y = f2b(f1.y); s1.z = f2b(f1.z); s1.w = f2b(f1.w);
        *(ushort4*)&As[ar][q8] = s0;
        *(ushort4*)&As[ar][q8 + 4] = s1;
        {
            int rho = tid >> 2;
            int g = rho >> 4, cn = rho & 15;
            *(uint4*)&Bs[rho][q8] =
                *(const uint4*)(WT + (size_t)(g * 256 + db * 16 + cn) * 768 + k0 + q8);
        }
        __syncthreads();
        short8v a = *(const short8v*)&As[w * 16 + lr][lk];
        #pragma unroll
        for (int g = 0; g < 4; ++g) {
            short8v b = *(const short8v*)&Bs[g * 16 + lr][lk];
            acc[g] = __builtin_amdgcn_mfma_f32_16x16x32_bf16(a, b, acc[g], 0, 0, 0);
        }
        __syncthreads();
    }

    const int rbase = (lane >> 4) * 4;
    const int d = db * 16 + lr;
    const float bi = bias[d], bf = bias[256 + d], bg = bias[512 + d], bo = bias[768 + d];
    #pragma unroll
    for (int r = 0; r < 4; ++r) {
        const int row = m0 + w * 16 + rbase + r;
        float i_ = acc[0][r] + bi;
        float f_ = acc[1][r] + bf;
        float g_ = acc[2][r] + bg;
        float o_ = acc[3][r] + bo;
        float cv = sigm(f_) * Cc[(size_t)row * 256 + d] + sigm(i_) * tanhf(g_);
        Cn[(size_t)row * 256 + d] = cv;
        Hn[(size_t)row * 256 + d] = sigm(o_) * tanhf(cv);
    }
}

// ---- iteration-0 LSTM: q_star=h=c=0 -> gates=bias (exact). Broadcast h0,c0 to all rows ----
__global__ __launch_bounds__(256) void lstm0_bcast_k(const float* __restrict__ bias,
                                                     float* __restrict__ Hn,
                                                     float* __restrict__ Cn, int M)
{
    int idx = blockIdx.x * 256 + threadIdx.x;
    if (idx >= M * 256) return;
    int d = idx & 255;
    float c0 = sigm(bias[d]) * tanhf(bias[512 + d]);
    float h0 = sigm(bias[768 + d]) * tanhf(c0);
    Cn[idx] = c0;
    Hn[idx] = h0;
}

// ---------------- prep kernels ----------------
__global__ __launch_bounds__(256) void prep_wt_k(const float* __restrict__ W,
                                                 bf16u* __restrict__ WT, int K, int KP)
{
    int idx = blockIdx.x * 256 + threadIdx.x;
    if (idx >= 256 * KP) return;
    int n = idx / KP, k = idx - n * KP;
    WT[idx] = (k < K) ? f2b(W[(size_t)k * H + n]) : (bf16u)0;
}

__global__ __launch_bounds__(256) void prep_wto_k(const float* __restrict__ Wo,
                                                  bf16u* __restrict__ WT)
{
    int idx = blockIdx.x * 256 + threadIdx.x;
    if (idx >= 256 * 416) return;
    int n = idx / 416, k = idx - n * 416;
    float v = 0.f;
    if (k < ATOM_FDIM) v = Wo[(size_t)k * H + n];
    else if (k >= 160) v = Wo[(size_t)(ATOM_FDIM + k - 160) * H + n];
    WT[idx] = f2b(v);
}

// merged mid-phase weight prep (single dispatch)
#define SZ_WTG   786432    // [1024][768]
#define SZ_WTNC  131072    // [256][512]
#define SZ_WTPQS 196608    // [768][256]
#define SZ_WTN1  262144    // [256][1024]
#define SZ_WTGC  131072    // [256][512]
__global__ __launch_bounds__(256) void prep_mid_k(
    const float* __restrict__ Wih_n, const float* __restrict__ Whh_n,
    const float* __restrict__ Wih_g, const float* __restrict__ Whh_g,
    const float* __restrict__ ncW,  const float* __restrict__ Wnn0,
    const float* __restrict__ Wnn0s, const float* __restrict__ Wnn1,
    const float* __restrict__ gcW,  const float* __restrict__ b_nn0s,
    bf16u* __restrict__ WTG_N, bf16u* __restrict__ WTG_G,
    bf16u* __restrict__ WT_NC, bf16u* __restrict__ WT_PQS,
    bf16u* __restrict__ WT_N1, bf16u* __restrict__ WT_GC,
    float* __restrict__ BIAS_PQS)
{
    int idx = blockIdx.x * 256 + threadIdx.x;
    if (idx < SZ_WTG) {
        int n = idx / 768, k = idx - n * 768;
        WTG_N[idx] = f2b(k < 512 ? Wih_n[(size_t)n * 512 + k] : Whh_n[(size_t)n * 256 + (k - 512)]);
        return;
    }
    idx -= SZ_WTG;
    if (idx < SZ_WTG) {
        int n = idx / 768, k = idx - n * 768;
        WTG_G[idx] = f2b(k < 512 ? Wih_g[(size_t)n * 512 + k] : Whh_g[(size_t)n * 256 + (k - 512)]);
        return;
    }
    idx -= SZ_WTG;
    if (idx < SZ_WTNC) {
        int n = idx / 512, k = idx - n * 512;
        WT_NC[idx] = f2b(ncW[(size_t)k * 256 + n]);
        return;
    }
    idx -= SZ_WTNC;
    if (idx < SZ_WTPQS) {
        int n = idx / 256, k = idx - n * 256;
        float v;
        if (n < 256)      v = Wnn0[(size_t)k * 256 + n];
        else if (n < 512) v = Wnn0[(size_t)(256 + k) * 256 + (n - 256)];
        else              v = Wnn0s[(size_t)k * 256 + (n - 512)];
        WT_PQS[idx] = f2b(v);
        return;
    }
    idx -= SZ_WTPQS;
    if (idx < SZ_WTN1) {
        int n = idx / 1024, k = idx - n * 1024;
        WT_N1[idx] = f2b(Wnn1[(size_t)k * 256 + n]);
        return;
    }
    idx -= SZ_WTN1;
    if (idx < SZ_WTGC) {
        int n = idx / 512, k = idx - n * 512;
        WT_GC[idx] = f2b(gcW[(size_t)k * 256 + n]);
        return;
    }
    idx -= SZ_WTGC;
    if (idx < 768) BIAS_PQS[idx] = (idx < 512) ? 0.f : b_nn0s[idx - 512];
}
#define PREP_MID_TOTAL (2 * SZ_WTG + SZ_WTNC + SZ_WTPQS + SZ_WTN1 + SZ_WTGC + 768)

__global__ __launch_bounds__(256) void prep_feat16_k(const float* __restrict__ F,
                                                     bf16u* __restrict__ O,
                                                     int rows, int K)
{
    int idx = blockIdx.x * 256 + threadIdx.x;
    if (idx >= rows * 160) return;
    int r = idx / 160, c = idx - r * 160;
    O[idx] = (c < K) ? f2b(F[(size_t)r * K + c]) : (bf16u)0;
}

// ---------------- small kernels ----------------
__global__ __launch_bounds__(256) void gather6_bf16_k(const bf16u* __restrict__ msg,
                                                      const int* __restrict__ a2b,
                                                      bf16u* __restrict__ outb)
{
    int idx = blockIdx.x * 256 + threadIdx.x;
    if (idx >= N_ATOMS * (H / 8)) return;
    int na = idx >> 5, c = idx & 31;
    const int* nb = a2b + (size_t)na * MAX_NB;
    float s[8] = {0.f, 0.f, 0.f, 0.f, 0.f, 0.f, 0.f, 0.f};
    #pragma unroll
    for (int j = 0; j < MAX_NB; ++j) {
        uint4 u = *(const uint4*)(msg + (size_t)nb[j] * H + c * 8);
        s[0] += b2f((bf16u)(u.x & 0xFFFFu)); s[1] += b2f((bf16u)(u.x >> 16));
        s[2] += b2f((bf16u)(u.y & 0xFFFFu)); s[3] += b2f((bf16u)(u.y >> 16));
        s[4] += b2f((bf16u)(u.z & 0xFFFFu)); s[5] += b2f((bf16u)(u.z >> 16));
        s[6] += b2f((bf16u)(u.w & 0xFFFFu)); s[7] += b2f((bf16u)(u.w >> 16));
    }
    uint4 o;
    o.x = (unsigned int)f2b(s[0]) | ((unsigned int)f2b(s[1]) << 16);
    o.y = (unsigned int)f2b(s[2]) | ((unsigned int)f2b(s[3]) << 16);
    o.z = (unsigned int)f2b(s[4]) | ((unsigned int)f2b(s[5]) << 16);
    o.w = (unsigned int)f2b(s[6]) | ((unsigned int)f2b(s[7]) << 16);
    *(uint4*)(outb + (size_t)na * H + c * 8) = o;
}

// feat bf16 (BF16F) or f32; h/q_star f32
template<bool BF16F>
__global__ __launch_bounds__(256) void s2s_attn_k(const void* __restrict__ featv,
                                                  const float* __restrict__ h,
                                                  float* __restrict__ q_star, int Nn)
{
    int m = blockIdx.x;
    int t = threadIdx.x;
    int lane = t & 63, wave = t >> 6;
    __shared__ float sc[32];
    const bf16u* fb = (const bf16u*)featv;
    const float* ff = (const float*)featv;
    const size_t fbase = (size_t)m * Nn * H;
    const float* hm = h + (size_t)m * H;
    for (int n = wave; n < Nn; n += 4) {
        float p = 0.f;
        if (BF16F) {
            ushort4 u = *(const ushort4*)(fb + fbase + (size_t)n * H + lane * 4);
            const float4 h4 = *(const float4*)(hm + lane * 4);
            p = b2f(u.x) * h4.x + b2f(u.y) * h4.y + b2f(u.z) * h4.z + b2f(u.w) * h4.w;
        } else {
            const float* fr = ff + fbase + (size_t)n * H;
            #pragma unroll
            for (int u = 0; u < 4; ++u) p += fr[lane * 4 + u] * hm[lane * 4 + u];
        }
        #pragma unroll
        for (int o = 32; o >= 1; o >>= 1) p += __shfl_xor(p, o);
        if (lane == 0) sc[n] = p;
    }
    __syncthreads();
    float mx = -1e30f;
    for (int n = 0; n < Nn; ++n) mx = fmaxf(mx, sc[n]);
    float ssum = 0.f, r = 0.f;
    for (int n = 0; n < Nn; ++n) {
        float a = expf(sc[n] - mx);
        ssum += a;
        float fv = BF16F ? b2f(fb[fbase + (size_t)n * H + t]) : ff[fbase + (size_t)n * H + t];
        r += a * fv;
    }
    r /= ssum;
    q_star[(size_t)m * (2 * H) + t] = hm[t];
    q_star[(size_t)m * (2 * H) + H + t] = r;
}

// X[b,s1,s2,:] from packed PQS [2048][768]: P = +0, Q = +256, SO = +512
__global__ __launch_bounds__(256) void build_x_k(const float* __restrict__ PQS,
                                                 const float* __restrict__ b0,
                                                 float* __restrict__ X)
{
    int idx = blockIdx.x * 256 + threadIdx.x;
    if (idx >= B_RXN * S_STEPS * S_STEPS * H) return;
    int d  = idx & 255;
    int s2 = (idx >> 8) & 3;
    int s1 = (idx >> 10) & 3;
    int b  = idx >> 12;
    float v;
    if (s1 == s2) v = PQS[((size_t)(b * S_STEPS + s1)) * 768 + 512 + d];
    else v = PQS[((size_t)(b * S_STEPS + s1)) * 768 + d]
           + PQS[((size_t)(b * S_STEPS + s2)) * 768 + 256 + d] + b0[d];
    X[idx] = v;
}

// ---------------- launch ----------------
extern "C" void kernel_launch(void* const* d_in, const int* in_sizes, int n_in,
                              void* d_out, int out_size, void* d_ws, size_t ws_size,
                              hipStream_t stream)
{
    const float* f_atoms   = (const float*)d_in[0];
    const float* f_bonds   = (const float*)d_in[1];
    const int*   a2b       = (const int*)d_in[2];
    const int*   b2a       = (const int*)d_in[3];
    const int*   b2revb    = (const int*)d_in[4];
    const float* W_i       = (const float*)d_in[5];
    const float* W_h       = (const float*)d_in[6];
    const float* W_o       = (const float*)d_in[7];
    const float* b_o       = (const float*)d_in[8];
    const float* W_nn0     = (const float*)d_in[9];
    const float* b_nn0     = (const float*)d_in[10];
    const float* W_nn0s    = (const float*)d_in[11];
    const float* b_nn0s    = (const float*)d_in[12];
    const float* W_nn1     = (const float*)d_in[13];
    const float* b_nn1     = (const float*)d_in[14];
    const float* lstm_n_Wih = (const float*)d_in[15];
    const float* lstm_n_Whh = (const float*)d_in[16];
    const float* lstm_n_b   = (const float*)d_in[17];
    const float* node_cond_W = (const float*)d_in[18];
    const float* node_cond_b = (const float*)d_in[19];
    const float* lstm_g_Wih = (const float*)d_in[20];
    const float* lstm_g_Whh = (const float*)d_in[21];
    const float* lstm_g_b   = (const float*)d_in[22];
    const float* graph_cond_W = (const float*)d_in[23];
    const float* graph_cond_b = (const float*)d_in[24];
    float* out = (float*)d_out;

    // ---- workspace layout (~235 MB) ----
    const size_t SZB = (size_t)NBP1 * H * sizeof(bf16u);    // 67,109,376 B
    char* base = (char*)d_ws;
    bf16u* INP  = (bf16u*)(base);                            // [NBP1,H]
    bf16u* MSG  = (bf16u*)(base + SZB);                      // [NBP1,H]
    bf16u* MW   = (bf16u*)(base + 2 * SZB);                  // [NBP1,H]
    bf16u* AMSG = (bf16u*)(base + 3 * SZB);                  // [N_ATOMS,H]
    bf16u* WT_I = (bf16u*)(base + 3 * SZB + 33554432);       // [256][160]
    bf16u* WT_H = (bf16u*)(base + 3 * SZB + 33636352);       // [256][256]
    bf16u* WT_O = (bf16u*)(base + 3 * SZB + 33767424);       // [256][416]
    // aliases:
    bf16u* FB16 = MW;                                        // before 1st MW
    bf16u* FA16 = MW;                                        // after last combine
    bf16u* ATOMH16 = (bf16u*)(base);                         // bf16 feat, alias INP (dead)
    float* SMALL = (float*)(base + SZB);                     // f32 scratch, alias MSG (dead)
    float* HN     = SMALL + 2097152;                         // [2048,256] (ping A)
    float* CN     = SMALL + 2621440;                         // [2048,256] (ping A)
    float* QSTARN = SMALL + 3145728;                         // [2048,512]
    float* MOL    = SMALL + 4194304;                         // [2048,256]
    float* PQS    = SMALL + 4718592;                         // [2048,768]
    float* XBUF   = SMALL + 6291456;                         // [8192,256]
    float* STEPS  = SMALL + 8388608;                         // [2048,256]
    float* HG     = SMALL + 8912896;                         // [512,256] (ping A)
    float* CG     = SMALL + 9043968;                         // [512,256] (ping A)
    float* QSTARG = SMALL + 9175040;                         // [512,512]
    float* HN2    = SMALL + 10485760;                        // [2048,256] (pong B)
    float* CN2    = SMALL + 11010048;                        // [2048,256] (pong B)
    float* HG2    = SMALL + 11534336;                        // [512,256]  (pong B)
    float* CG2    = SMALL + 11665408;                        // [512,256]  (pong B)
    char* sm2 = base + 2 * SZB + 25165824;                   // MW dead zone
    bf16u* WTG_N   = (bf16u*)(sm2);                  // [1024][768]
    bf16u* WTG_G   = (bf16u*)(sm2 + 1572864);        // [1024][768]
    bf16u* WT_NC   = (bf16u*)(sm2 + 3145728);        // [256][512]
    bf16u* WT_PQS  = (bf16u*)(sm2 + 3407872);        // [768][256]
    bf16u* WT_N1   = (bf16u*)(sm2 + 3801088);        // [256][1024]
    bf16u* WT_GC   = (bf16u*)(sm2 + 4325376);        // [256][512]
    float* BIAS_PQS = (float*)(sm2 + 4587520);       // [768]

    dim3 blk(256), blk5(512);
    const int MB_BOND = (NBP1 + 127) / 128;   // 1025
    const int MB_ATOM = N_ATOMS / 128;        // 512
    const int G_GATH = (N_ATOMS * (H / 8) + 255) / 256;
    const int G_COMB = (NBP1 * 32 + 255) / 256;

    // 0. weight + input prep
    prep_wt_k<<<(256 * 160 + 255) / 256, blk, 0, stream>>>(W_i, WT_I, BOND_FDIM, 160);
    prep_wt_k<<<(256 * 256 + 255) / 256, blk, 0, stream>>>(W_h, WT_H, H, 256);
    prep_wto_k<<<(256 * 416 + 255) / 256, blk, 0, stream>>>(W_o, WT_O);
    prep_feat16_k<<<(int)(((size_t)NBP1 * 160 + 255) / 256), blk, 0, stream>>>(
        f_bonds, FB16, NBP1, BOND_FDIM);

    // 1. INP = FB16 @ W_i
    dense_gemm_k<0, false><<<MB_BOND, blk5, 0, stream>>>(
        FB16, nullptr, WT_I, nullptr, INP, NBP1);

    // 2. depth loop
    dense_gemm_k<1, true><<<MB_BOND, blk5, 0, stream>>>(
        INP, nullptr, WT_H, nullptr, MW, NBP1);
    gather6_bf16_k<<<G_GATH, blk, 0, stream>>>(MW, a2b, AMSG);
    combine_k<<<G_COMB, blk, 0, stream>>>(INP, AMSG, MW, b2a, b2revb, MSG);
    dense_gemm_k<1, false><<<MB_BOND, blk5, 0, stream>>>(
        MSG, nullptr, WT_H, nullptr, MW, NBP1);
    gather6_bf16_k<<<G_GATH, blk, 0, stream>>>(MW, a2b, AMSG);
    combine_k<<<G_COMB, blk, 0, stream>>>(INP, AMSG, MW, b2a, b2revb, MSG);

    // 3. nei = gather6(final MSG)
    gather6_bf16_k<<<G_GATH, blk, 0, stream>>>(MSG, a2b, AMSG);

    // 3b. packed f_atoms + merged mid-phase weight prep (MW region dead)
    prep_feat16_k<<<(N_ATOMS * 160 + 255) / 256, blk, 0, stream>>>(
        f_atoms, FA16, N_ATOMS, ATOM_FDIM);
    prep_mid_k<<<(PREP_MID_TOTAL + 255) / 256, blk, 0, stream>>>(
        lstm_n_Wih, lstm_n_Whh, lstm_g_Wih, lstm_g_Whh,
        node_cond_W, W_nn0, W_nn0s, W_nn1, graph_cond_W, b_nn0s,
        WTG_N, WTG_G, WT_NC, WT_PQS, WT_N1, WT_GC, BIAS_PQS);

    // 4. atom_h = relu([f_atoms, nei] @ W_o + b_o) -> ATOMH16 bf16
    dense_gemm_k<2, false><<<MB_ATOM, blk5, 0, stream>>>(
        FA16, AMSG, WT_O, b_o, ATOMH16, N_ATOMS);

    // 5. node Set2Set over [2048, 32, 256]
    {
        // iter 0: gates = bias exactly (q_star = h = c = 0)
        lstm0_bcast_k<<<(N_MOLS * H + 255) / 256, blk, 0, stream>>>(lstm_n_b, HN, CN, N_MOLS);
        s2s_attn_k<true><<<N_MOLS, blk, 0, stream>>>(ATOMH16, HN, QSTARN, ATOMS_PER_MOL);
        float *hc = HN, *cc = CN, *hn = HN2, *cn = CN2;
        for (int it = 1; it < N_ITERS; ++it) {
            gates_lstm_k<<<dim3(N_MOLS / 64, 16), blk, 0, stream>>>(
                QSTARN, hc, cc, WTG_N, lstm_n_b, hn, cn, N_MOLS);
            s2s_attn_k<true><<<N_MOLS, blk, 0, stream>>>(ATOMH16, hn, QSTARN, ATOMS_PER_MOL);
            float* t;
            t = hc; hc = hn; hn = t;
            t = cc; cc = cn; cn = t;
        }
    }
    lin64_k<true><<<dim3(N_MOLS / 64, 4), blk, 0, stream>>>(
        QSTARN, 2 * H, 2 * H, QSTARN, 2 * H, WT_NC, 2 * H, node_cond_b, MOL, H, 2 * H);

    // 6. NN attention over steps (fused P|Q|SO GEMM)
    lin64_k<true><<<dim3(N_MOLS / 64, 12), blk, 0, stream>>>(
        MOL, H, H, MOL, H, WT_PQS, H, BIAS_PQS, PQS, 3 * H, H);
    build_x_k<<<(B_RXN * 16 * H) / 256, blk, 0, stream>>>(PQS, b_nn0, XBUF);
    lin64_k<true><<<dim3(N_MOLS / 64, 4), blk, 0, stream>>>(
        XBUF, S_STEPS * H, S_STEPS * H, XBUF, S_STEPS * H, WT_N1, S_STEPS * H, b_nn1,
        STEPS, H, S_STEPS * H);

    // 7. graph Set2Set over [512, 4, 256]
    {
        lstm0_bcast_k<<<(B_RXN * H + 255) / 256, blk, 0, stream>>>(lstm_g_b, HG, CG, B_RXN);
        s2s_attn_k<false><<<B_RXN, blk, 0, stream>>>(STEPS, HG, QSTARG, S_STEPS);
        float *hc = HG, *cc = CG, *hn = HG2, *cn = CG2;
        for (int it = 1; it < N_ITERS; ++it) {
            gates_lstm_k<<<dim3(B_RXN / 64, 16), blk, 0, stream>>>(
                QSTARG, hc, cc, WTG_G, lstm_g_b, hn, cn, B_RXN);
            s2s_attn_k<false><<<B_RXN, blk, 0, stream>>>(STEPS, hn, QSTARG, S_STEPS);
            float* t;
            t = hc; hc = hn; hn = t;
            t = cc; cc = cn; cn = t;
        }
    }

    // 8. out
    lin64_k<true><<<dim3(B_RXN / 64, 4), blk, 0, stream>>>(
        QSTARG, 2 * H, 2 * H, QSTARG, 2 * H, WT_GC, 2 * H, graph_cond_b, out, H, 2 * H);
}